// Round 8
// baseline (608.929 us; speedup 1.0000x reference)
//
#include <hip/hip_runtime.h>
#include <stdint.h>

typedef unsigned short u16;
typedef __attribute__((ext_vector_type(4))) float f32x4;
typedef __attribute__((ext_vector_type(8))) __bf16 bf16x8;
typedef __attribute__((ext_vector_type(8))) unsigned short u16x8;

#define T_ 1024
#define D_ 1024
#define HD_ 64

__device__ __forceinline__ float b2f(u16 u) {
    union { unsigned int i; float f; } x; x.i = ((unsigned int)u) << 16; return x.f;
}
__device__ __forceinline__ u16 f2b(float f) {
    union { float f; unsigned int i; } x; x.f = f;
    unsigned int i = x.i;
    unsigned int r = (i >> 16) & 1;
    i += 0x7fffu + r;
    return (u16)(i >> 16);
}

// async global->LDS, 16B per lane; LDS dest is wave-uniform base + lane*16
__device__ __forceinline__ void gl2lds16(const void* g, void* l) {
    auto gp = (const __attribute__((address_space(1))) unsigned int*)(unsigned long long)(g);
    auto lp = (__attribute__((address_space(3))) unsigned int*)(unsigned int)(unsigned long long)(l);
    __builtin_amdgcn_global_load_lds(gp, lp, 16, 0, 0);
}

__device__ __forceinline__ float wred_sum(float v) {
    #pragma unroll
    for (int o = 32; o > 0; o >>= 1) v += __shfl_down(v, o, 64);
    return v;
}
__device__ __forceinline__ float shx(float v, int m) { return __shfl_xor(v, m, 64); }

// ---------------- f32 transpose + bf16 convert: out[c*R + r] = bf16(in[r*C + c]) ----
__global__ __launch_bounds__(256) void transpose_cvt(const float* __restrict__ in,
                                                     u16* __restrict__ out, int R, int C) {
    __shared__ float Ts[64][65];
    int c0 = blockIdx.x * 64, r0 = blockIdx.y * 64;
    int tid = threadIdx.x, tx = tid & 63, ty = tid >> 6;
    #pragma unroll
    for (int i = ty; i < 64; i += 4) Ts[i][tx] = in[(long)(r0 + i) * C + c0 + tx];
    __syncthreads();
    #pragma unroll
    for (int i = ty; i < 64; i += 4)
        out[(long)(c0 + i) * R + r0 + tx] = f2b(Ts[tx][i]);
}

// ---- f32 transpose + hi/lo split: W[R,C] -> out[C, 3R] = [hi | hi | lo] ------------
__global__ __launch_bounds__(256) void transpose_split(const float* __restrict__ in,
                                                       u16* __restrict__ out, int R, int C) {
    __shared__ float Ts[64][65];
    int c0 = blockIdx.x * 64, r0 = blockIdx.y * 64;
    int tid = threadIdx.x, tx = tid & 63, ty = tid >> 6;
    #pragma unroll
    for (int i = ty; i < 64; i += 4) Ts[i][tx] = in[(long)(r0 + i) * C + c0 + tx];
    __syncthreads();
    #pragma unroll
    for (int i = ty; i < 64; i += 4) {
        float v = Ts[tx][i];
        u16 hi = f2b(v);
        u16 lo = f2b(v - b2f(hi));
        long base = (long)(c0 + i) * (3 * R) + r0 + tx;
        out[base] = hi;
        out[base + R] = hi;
        out[base + 2 * R] = lo;
    }
}

// ---- f32 rowwise hi/lo split: X[M,1024] -> out[M, 3072] = [hi | lo | hi] -----------
__global__ __launch_bounds__(256) void split_rows(const float* __restrict__ in,
                                                  u16* __restrict__ out) {
    long row = blockIdx.x;
    int tid = threadIdx.x;
    #pragma unroll
    for (int k = 0; k < 4; k++) {
        int c = tid + k * 256;
        float v = in[row * 1024 + c];
        u16 hi = f2b(v);
        u16 lo = f2b(v - b2f(hi));
        out[row * 3072 + c] = hi;
        out[row * 3072 + 1024 + c] = lo;
        out[row * 3072 + 2048 + c] = hi;
    }
}

// ------- m97-style BT GEMM, 1-barrier prefetch pipeline, z-batched ------------------
enum { EPI_F32_BIAS = 0, EPI_BF16_BIAS = 1, EPI_BF16_BIAS_RELU = 2 };

template <int EPI, int BN>
__global__ __launch_bounds__(256) void gemm128(
    const u16* __restrict__ A, const u16* __restrict__ B, void* __restrict__ C,
    const float* __restrict__ bias,
    int M, int N, int K, int lda, int ldb, int ldc,
    long sAz, long sBz, long sCz) {
    __shared__ u16 As[2][128 * 32];
    __shared__ u16 Bs[2][BN * 32];
    const int tid = threadIdx.x, wave = tid >> 6, lane = tid & 63;
    const int m0 = blockIdx.x * 128, n0 = blockIdx.y * BN;
    const int z = blockIdx.z;
    const u16* Ab = A + (long)z * sAz;
    const u16* Bb = B + (long)z * sBz;
    const int srow = lane >> 2, scol = (lane & 3) * 8;
    constexpr int IT = (BN == 128) ? 4 : 2;
    f32x4 acc[IT][4];
    #pragma unroll
    for (int i = 0; i < IT; i++)
        #pragma unroll
        for (int j = 0; j < 4; j++) acc[i][j] = (f32x4){0.f, 0.f, 0.f, 0.f};
    const int wm = (BN == 128) ? (wave >> 1) * 64 : wave * 32;
    const int wn = (BN == 128) ? (wave & 1) * 64 : 0;
    const int fr = lane & 15, fk = (lane >> 4) * 8;

    // prologue: stage k0=0 into buf 0
    {
        #pragma unroll
        for (int t = 0; t < 2; t++) {
            int rb = wave * 32 + t * 16;
            gl2lds16(Ab + (long)(m0 + rb + srow) * lda + scol, &As[0][rb * 32]);
        }
        if constexpr (BN == 128) {
            #pragma unroll
            for (int t = 0; t < 2; t++) {
                int rb = wave * 32 + t * 16;
                gl2lds16(Bb + (long)(n0 + rb + srow) * ldb + scol, &Bs[0][rb * 32]);
            }
        } else {
            int rb = wave * 16;
            gl2lds16(Bb + (long)(n0 + rb + srow) * ldb + scol, &Bs[0][rb * 32]);
        }
    }
    __syncthreads();

    for (int k0 = 0; k0 < K; k0 += 32) {
        const int buf = (k0 >> 5) & 1;
        const int kn = k0 + 32;
        if (kn < K) {   // prefetch next tile into buf^1 (overlaps with compute below)
            #pragma unroll
            for (int t = 0; t < 2; t++) {
                int rb = wave * 32 + t * 16;
                gl2lds16(Ab + (long)(m0 + rb + srow) * lda + kn + scol, &As[buf ^ 1][rb * 32]);
            }
            if constexpr (BN == 128) {
                #pragma unroll
                for (int t = 0; t < 2; t++) {
                    int rb = wave * 32 + t * 16;
                    gl2lds16(Bb + (long)(n0 + rb + srow) * ldb + kn + scol, &Bs[buf ^ 1][rb * 32]);
                }
            } else {
                int rb = wave * 16;
                gl2lds16(Bb + (long)(n0 + rb + srow) * ldb + kn + scol, &Bs[buf ^ 1][rb * 32]);
            }
        }
        bf16x8 af[IT], bv[4];
        #pragma unroll
        for (int i = 0; i < IT; i++) af[i] = *(const bf16x8*)&As[buf][(wm + i * 16 + fr) * 32 + fk];
        #pragma unroll
        for (int j = 0; j < 4; j++) bv[j] = *(const bf16x8*)&Bs[buf][(wn + j * 16 + fr) * 32 + fk];
        #pragma unroll
        for (int i = 0; i < IT; i++)
            #pragma unroll
            for (int j = 0; j < 4; j++)
                acc[i][j] = __builtin_amdgcn_mfma_f32_16x16x32_bf16(af[i], bv[j], acc[i][j], 0, 0, 0);
        __syncthreads();   // drains prefetch vmcnt (overlapped) + guards buf reuse
    }
    const int er = (lane >> 4) * 4, ec = lane & 15;
    #pragma unroll
    for (int i = 0; i < IT; i++)
        #pragma unroll
        for (int j = 0; j < 4; j++)
            #pragma unroll
            for (int r = 0; r < 4; r++) {
                const int gm = m0 + wm + i * 16 + er + r;
                const int gn = n0 + wn + j * 16 + ec;
                const float v = acc[i][j][r];
                if constexpr (EPI == EPI_F32_BIAS) {
                    ((float*)C)[(long)z * sCz + (long)gm * ldc + gn] = v + bias[gn];
                } else if constexpr (EPI == EPI_BF16_BIAS) {
                    ((u16*)C)[(long)z * sCz + (long)gm * ldc + gn] = f2b(v + bias[gn]);
                } else {
                    ((u16*)C)[(long)z * sCz + (long)gm * ldc + gn] = f2b(fmaxf(v + bias[gn], 0.0f));
                }
            }
}

// ---------------- repack V^T: Vt[s,z,d,t] = U/Vf[b*T+t, 2048+h*64+d] ----------------
__global__ __launch_bounds__(256) void repack_vt(const float* __restrict__ Uf,
                                                 const float* __restrict__ Vf,
                                                 u16* __restrict__ Vt) {
    __shared__ u16 Ts[64][65];
    int tid = threadIdx.x, tx = tid & 63, ty = tid >> 6;
    int t0 = blockIdx.x * 64;
    int sz = blockIdx.y, s = sz >> 5, z = sz & 31, b = z >> 4, h = z & 15;
    const float* srcp = s ? Vf : Uf;
    #pragma unroll
    for (int i = ty; i < 64; i += 4)
        Ts[i][tx] = f2b(srcp[(long)(b * T_ + t0 + i) * 3072 + 2048 + h * 64 + tx]);
    __syncthreads();
    u16* dst = Vt + (long)sz * HD_ * T_;
    #pragma unroll
    for (int i = ty; i < 64; i += 4) dst[(long)i * T_ + t0 + tx] = Ts[tx][i];
}

// ---- R/S partials: RSp[chunk][idx][d1*64+d2] = sum_{j in chunk} mask*k[j,d1]*q[j,d2]
__global__ __launch_bounds__(256) void rs_part(const float* __restrict__ Uf,
                                               const float* __restrict__ Vf,
                                               const int* __restrict__ smask,
                                               const int* __restrict__ amask,
                                               float* __restrict__ RSp) {
    __shared__ float Ksh[64 * 64];
    __shared__ float Qsh[64 * 64];
    int idx = blockIdx.x;
    int mat = idx >> 5, z = idx & 31, b = z >> 4, h = z & 15;
    int chunk = blockIdx.y, j0 = chunk * 64;
    const float* base = mat ? Uf : Vf;
    const int* mk = mat ? smask : amask;
    int tid = threadIdx.x;
    float4* K4 = (float4*)Ksh;
    float4* Q4 = (float4*)Qsh;
    for (int ii = tid; ii < 1024; ii += 256) {
        int j = ii >> 4, d4 = ii & 15;
        long row = (long)(b * T_ + j0 + j) * 3072 + h * 64;
        int m = mk[b * T_ + j0 + j];
        float4 kv = ((const float4*)&base[row + 1024])[d4];
        if (m <= 0) kv = (float4){0.f, 0.f, 0.f, 0.f};
        K4[ii] = kv;
        Q4[ii] = ((const float4*)&base[row])[d4];
    }
    __syncthreads();
    int d1 = tid >> 2, c0 = (tid & 3) * 16;
    float4 a[4];
    #pragma unroll
    for (int k = 0; k < 4; k++) a[k] = (float4){0.f, 0.f, 0.f, 0.f};
    for (int j = 0; j < 64; j++) {
        float kv = Ksh[j * 64 + d1];
        const float4* q = (const float4*)&Qsh[j * 64 + c0];
        #pragma unroll
        for (int k = 0; k < 4; k++) {
            float4 qv = q[k];
            a[k].x += kv * qv.x; a[k].y += kv * qv.y;
            a[k].z += kv * qv.z; a[k].w += kv * qv.w;
        }
    }
    float4* out = (float4*)&RSp[((long)chunk * 64 + idx) * 4096 + d1 * 64 + c0];
    #pragma unroll
    for (int k = 0; k < 4; k++) out[k] = a[k];
}

// ---- RS[idx][e] = sum_{chunk<16} RSp[chunk][idx][e]  (float4-wide) -----------------
__global__ __launch_bounds__(256) void rs_reduce(const float* __restrict__ RSp,
                                                 float* __restrict__ RS) {
    int gid = blockIdx.x * 256 + threadIdx.x;    // 65536 float4s
    const float4* in = (const float4*)RSp;
    float4 s = (float4){0.f, 0.f, 0.f, 0.f};
    #pragma unroll
    for (int c = 0; c < 16; c++) {
        float4 v = in[(long)c * 65536 + gid];
        s.x += v.x; s.y += v.y; s.z += v.z; s.w += v.w;
    }
    ((float4*)RS)[gid] = s;
}

// ---------------- Q' = (Q @ R)/64, hi/lo split to [qhi|qlo] (128) -------------------
__global__ __launch_bounds__(256) void qprime(const float* __restrict__ Uf,
                                              const float* __restrict__ Vf,
                                              const float* __restrict__ RS,
                                              u16* __restrict__ Qs) {
    __shared__ float Rm[4096];
    __shared__ float Qsh[128][65];
    int t0 = blockIdx.x * 128;
    int sz = blockIdx.y, s = sz >> 5, z = sz & 31, b = z >> 4, h = z & 15;
    const float* Qf = s ? Vf : Uf;
    const float* mat = RS + (long)(s * 32 + z) * 4096;
    int tid = threadIdx.x;
    for (int ii = tid; ii < 1024; ii += 256)
        ((float4*)Rm)[ii] = ((const float4*)mat)[ii];
    for (int ii = tid; ii < 2048; ii += 256) {
        int j = ii >> 4, d4 = ii & 15;
        float4 v = ((const float4*)&Qf[(long)(b * T_ + t0 + j) * 3072 + h * 64])[d4];
        Qsh[j][d4 * 4] = v.x; Qsh[j][d4 * 4 + 1] = v.y;
        Qsh[j][d4 * 4 + 2] = v.z; Qsh[j][d4 * 4 + 3] = v.w;
    }
    __syncthreads();
    int r = tid >> 1, c0 = (tid & 1) * 32;
    float4 acc[8];
    #pragma unroll
    for (int k = 0; k < 8; k++) acc[k] = (float4){0.f, 0.f, 0.f, 0.f};
    for (int d1 = 0; d1 < 64; d1++) {
        float q = Qsh[r][d1];
        const float4* rm = (const float4*)&Rm[d1 * 64 + c0];
        #pragma unroll
        for (int k = 0; k < 8; k++) {
            float4 rv = rm[k];
            acc[k].x += q * rv.x; acc[k].y += q * rv.y;
            acc[k].z += q * rv.z; acc[k].w += q * rv.w;
        }
    }
    u16 hiA[32], loA[32];
    #pragma unroll
    for (int k = 0; k < 8; k++) {
        #pragma unroll
        for (int e = 0; e < 4; e++) {
            float x = ((const float*)&acc[k])[e] * (1.f / 64.f);
            int c = k * 4 + e;
            u16 hi = f2b(x);
            hiA[c] = hi;
            loA[c] = f2b(x - b2f(hi));
        }
    }
    u16* out = Qs + ((long)sz * T_ + (t0 + r)) * 128;
    #pragma unroll
    for (int i = 0; i < 4; i++) {
        *(u16x8*)&out[c0 + i * 8]      = *(const u16x8*)&hiA[i * 8];
        *(u16x8*)&out[64 + c0 + i * 8] = *(const u16x8*)&loA[i * 8];
    }
}

// ---------------- K split to [khi|klo] (128), masked rows zeroed --------------------
__global__ __launch_bounds__(256) void ksplit(const float* __restrict__ Uf,
                                              const float* __restrict__ Vf,
                                              const int* __restrict__ src_mask,
                                              const int* __restrict__ aux_mask,
                                              u16* __restrict__ Ks) {
    int t0 = blockIdx.x * 64;
    int sz = blockIdx.y, s = sz >> 5, z = sz & 31, b = z >> 4, h = z & 15;
    const float* Kf = s ? Vf : Uf;
    const int* mk = s ? aux_mask : src_mask;
    int tid = threadIdx.x;
    #pragma unroll
    for (int uu = 0; uu < 4; uu++) {
        int u = tid + uu * 256;             // 0..1023 = 64 rows x 16 16B-units
        int lr = u >> 4;
        int s16 = u & 15;                   // 0..15
        int seg = s16 >> 3;                 // 0:hi 1:lo
        int off = (s16 & 7) * 8;            // 0..56
        int r = t0 + lr;
        int m = mk[b * T_ + r];
        const float* srcp = &Kf[(long)(b * T_ + r) * 3072 + 1024 + h * 64 + off];
        float4 va = ((const float4*)srcp)[0];
        float4 vb = ((const float4*)srcp)[1];
        float xs[8] = {va.x, va.y, va.z, va.w, vb.x, vb.y, vb.z, vb.w};
        u16x8 wv;
        #pragma unroll
        for (int e = 0; e < 8; e++) {
            float x = (m > 0) ? xs[e] : 0.0f;
            u16 hi = f2b(x);
            wv[e] = (seg == 1) ? f2b(x - b2f(hi)) : hi;
        }
        *(u16x8*)&Ks[((long)sz * T_ + r) * 128 + seg * 64 + off] = wv;
    }
}

// ------- fused flash attention: comb = Q'K^T (logical K=192 via 128-phys hi/lo) -----
// 512 threads (8 waves x 16 q-rows), KVBLK=32, K/V double-buffered, 32KB LDS ->
// 3-4 blocks/CU. Fragment-reuse: 6 logical K-groups from 4 phys Q x 4 phys K frags.
__global__ __launch_bounds__(512, 6) void flash_comb(const u16* __restrict__ Qs,
                                                     const u16* __restrict__ Ks,
                                                     const u16* __restrict__ Vt,
                                                     u16* __restrict__ ctx2) {
    __shared__ u16 Ksh[2][32 * 128]; // [buf][row][u16; unit c16 ^ (row&7)], 8KB each
    __shared__ u16 Vsh[2][64 * 32];  // [buf][d][unit c16 ^ ((d^(d>>2))&3)], 4KB each
    __shared__ u16 Psh[128 * 32];    // [q][col ^ pswz(q)], 8KB
    const int tid = threadIdx.x, wave = tid >> 6, lane = tid & 63;
    const int z = blockIdx.x;
    const int m0 = blockIdx.y * 128;
    const int h = z & 15;
    const int g = lane >> 4, fr = lane & 15;
    const int wm = wave * 16;
    const u16* Qb = Qs + (long)z * T_ * 128;
    const u16* Kb = Ks + (long)z * T_ * 128;
    const u16* Vb = Vt + (long)z * HD_ * T_;

    // staging: 12 1KB slots (8 K + 4 V); wave w: slots {w, w+8<12}
    auto STAGE = [&](int k0, int buf) {
        #pragma unroll
        for (int t = 0; t < 2; t++) {
            int slot = wave + t * 8;
            if (slot < 8) {          // K: 32 rows x 16 units
                int o16 = slot * 64 + lane;
                int row = o16 >> 4, c16 = o16 & 15;
                gl2lds16(Kb + (long)(k0 + row) * 128 + ((c16 ^ (row & 7)) * 8),
                         &Ksh[buf][slot * 512]);
            } else if (slot < 12) {  // V: 64 d-rows x 4 units
                int o16 = (slot - 8) * 64 + lane;
                int d = o16 >> 2, c16 = o16 & 3;
                gl2lds16(Vb + (long)d * T_ + k0 + ((c16 ^ ((d ^ (d >> 2)) & 3)) * 8),
                         &Vsh[buf][(slot - 8) * 512]);
            }
        }
    };

    // Q' phys fragments (4): [qhi g0, qhi g1, qlo g0, qlo g1]
    bf16x8 qA[4];
    #pragma unroll
    for (int p = 0; p < 4; p++)
        qA[p] = *(const bf16x8*)&Qb[(long)(m0 + wm + fr) * 128 + p * 32 + g * 8];

    f32x4 oacc[4], mrun, lrun;
    mrun = (f32x4){-1e30f, -1e30f, -1e30f, -1e30f};
    lrun = (f32x4){0.f, 0.f, 0.f, 0.f};
    #pragma unroll
    for (int dj = 0; dj < 4; dj++) oacc[dj] = (f32x4){0.f, 0.f, 0.f, 0.f};

    STAGE(0, 0);
    __syncthreads();

    #pragma unroll 1
    for (int kt = 0; kt < 32; kt++) {
        const int buf = kt & 1;
        if (kt < 31) STAGE((kt + 1) * 32, buf ^ 1);   // prefetch overlaps compute

        // S = Q' K^T (16 q-rows x 32 k-cols), logical K=192 via fragment reuse
        f32x4 sacc[2];
        sacc[0] = (f32x4){0.f, 0.f, 0.f, 0.f};
        sacc[1] = (f32x4){0.f, 0.f, 0.f, 0.f};
        __builtin_amdgcn_s_setprio(1);
        {
            bf16x8 kb[2][2];
            #pragma unroll
            for (int pk = 0; pk < 2; pk++)
                #pragma unroll
                for (int ki = 0; ki < 2; ki++) {
                    int row = ki * 16 + fr;
                    kb[pk][ki] = *(const bf16x8*)&Ksh[buf][row * 128 + (((pk * 4 + g) ^ (row & 7)) * 8)];
                }
            // (q0,k0) (q1,k1) (q2,k0) (q3,k1)
            #pragma unroll
            for (int ki = 0; ki < 2; ki++) {
                sacc[ki] = __builtin_amdgcn_mfma_f32_16x16x32_bf16(qA[0], kb[0][ki], sacc[ki], 0, 0, 0);
                sacc[ki] = __builtin_amdgcn_mfma_f32_16x16x32_bf16(qA[1], kb[1][ki], sacc[ki], 0, 0, 0);
                sacc[ki] = __builtin_amdgcn_mfma_f32_16x16x32_bf16(qA[2], kb[0][ki], sacc[ki], 0, 0, 0);
                sacc[ki] = __builtin_amdgcn_mfma_f32_16x16x32_bf16(qA[3], kb[1][ki], sacc[ki], 0, 0, 0);
            }
            // (q0,k2) (q1,k3): reload klo into kb
            #pragma unroll
            for (int pk = 0; pk < 2; pk++)
                #pragma unroll
                for (int ki = 0; ki < 2; ki++) {
                    int row = ki * 16 + fr;
                    kb[pk][ki] = *(const bf16x8*)&Ksh[buf][row * 128 + ((((pk + 2) * 4 + g) ^ (row & 7)) * 8)];
                }
            #pragma unroll
            for (int ki = 0; ki < 2; ki++) {
                sacc[ki] = __builtin_amdgcn_mfma_f32_16x16x32_bf16(qA[0], kb[0][ki], sacc[ki], 0, 0, 0);
                sacc[ki] = __builtin_amdgcn_mfma_f32_16x16x32_bf16(qA[1], kb[1][ki], sacc[ki], 0, 0, 0);
            }
        }
        __builtin_amdgcn_s_setprio(0);

        // online softmax in C-layout: row = wm + g*4+e, col = ki*16+fr
        f32x4 tm;
        #pragma unroll
        for (int e = 0; e < 4; e++) tm[e] = fmaxf(sacc[0][e], sacc[1][e]);
        #pragma unroll
        for (int off = 1; off < 16; off <<= 1)
            #pragma unroll
            for (int e = 0; e < 4; e++) tm[e] = fmaxf(tm[e], shx(tm[e], off));

        // defer-max (T13): only rescale when tile max grew past mrun + 8
        int within = (tm[0] <= mrun[0] + 8.f) && (tm[1] <= mrun[1] + 8.f) &&
                     (tm[2] <= mrun[2] + 8.f) && (tm[3] <= mrun[3] + 8.f);
        if (!__all(within)) {
            f32x4 alpha;
            #pragma unroll
            for (int e = 0; e < 4; e++) {
                float mnew = fmaxf(mrun[e], tm[e]);
                alpha[e] = __expf(mrun[e] - mnew);
                mrun[e] = mnew;
            }
            #pragma unroll
            for (int dj = 0; dj < 4; dj++)
                #pragma unroll
                for (int e = 0; e < 4; e++) oacc[dj][e] *= alpha[e];
            #pragma unroll
            for (int e = 0; e < 4; e++) lrun[e] *= alpha[e];
        }

        f32x4 psum = (f32x4){0.f, 0.f, 0.f, 0.f};
        #pragma unroll
        for (int ki = 0; ki < 2; ki++) {
            #pragma unroll
            for (int e = 0; e < 4; e++) {
                float p = __expf(sacc[ki][e] - mrun[e]);
                psum[e] += p;
                int row = wm + g * 4 + e;
                int ps = ((row ^ (row >> 2)) & 3) << 3;
                Psh[row * 32 + ((ki * 16 + fr) ^ ps)] = f2b(p);
            }
        }
        #pragma unroll
        for (int off = 1; off < 16; off <<= 1)
            #pragma unroll
            for (int e = 0; e < 4; e++) psum[e] += shx(psum[e], off);
        #pragma unroll
        for (int e = 0; e < 4; e++) lrun[e] += psum[e];

        // PV: O += P @ V (P via LDS round-trip C-layout -> A-layout, wave-private)
        bf16x8 pa;
        {
            int row = wm + fr;
            pa = *(const bf16x8*)&Psh[row * 32 + ((g ^ ((row ^ (row >> 2)) & 3)) * 8)];
        }
        __builtin_amdgcn_s_setprio(1);
        #pragma unroll
        for (int dj = 0; dj < 4; dj++) {
            int d = dj * 16 + fr;
            bf16x8 vb = *(const bf16x8*)&Vsh[buf][d * 32 + ((g ^ ((d ^ (d >> 2)) & 3)) * 8)];
            oacc[dj] = __builtin_amdgcn_mfma_f32_16x16x32_bf16(pa, vb, oacc[dj], 0, 0, 0);
        }
        __builtin_amdgcn_s_setprio(0);
        __syncthreads();   // drains prefetch vmcnt (overlapped) + guards buf reuse
    }

    // epilogue: O /= l; ctx2 flat [4096][1024], row = (z>>4)*T + qr
    f32x4 inv;
    #pragma unroll
    for (int e = 0; e < 4; e++) inv[e] = 1.f / lrun[e];
    #pragma unroll
    for (int dj = 0; dj < 4; dj++)
        #pragma unroll
        for (int e = 0; e < 4; e++) {
            int qr = m0 + wm + g * 4 + e;
            int dc = dj * 16 + fr;
            ctx2[((long)((z >> 4) * T_ + qr)) * D_ + h * 64 + dc] = f2b(oacc[dj][e] * inv[e]);
        }
}

// ------- fused residual-add + LayerNorm, dual-stream batched (4096 rows) ------------
template <bool XF32, bool OUTF32>
__global__ __launch_bounds__(256) void ln_fused2(const void* __restrict__ x0,
                                                 const void* __restrict__ x1,
                                                 const u16* __restrict__ y,
                                                 const float* __restrict__ g,
                                                 const float* __restrict__ be,
                                                 void* __restrict__ out) {
    __shared__ float red[8];
    int row = blockIdx.x;
    const void* xp = (row < 2048) ? x0 : x1;
    long xbase = (long)((row < 2048) ? row : row - 2048) * 1024;
    long base = (long)row * 1024;
    int tid = threadIdx.x, wave = tid >> 6, lane = tid & 63;
    float v[4];
    #pragma unroll
    for (int i = 0; i < 4; i++) {
        int c = tid + i * 256;
        float xv = XF32 ? ((const float*)xp)[xbase + c] : b2f(((const u16*)xp)[xbase + c]);
        v[i] = xv + b2f(y[base + c]);
    }
    float s = v[0] + v[1] + v[2] + v[3];
    float q = v[0] * v[0] + v[1] * v[1] + v[2] * v[2] + v[3] * v[3];
    s = wred_sum(s);
    q = wred_sum(q);
    if (lane == 0) { red[wave] = s; red[4 + wave] = q; }
    __syncthreads();
    s = red[0] + red[1] + red[2] + red[3];
    q = red[4] + red[5] + red[6] + red[7];
    float mean = s * (1.f / 1024.f);
    float var = q * (1.f / 1024.f) - mean * mean;
    float inv = rsqrtf(var + 1e-5f);
    #pragma unroll
    for (int i = 0; i < 4; i++) {
        int c = tid + i * 256;
        float o = (v[i] - mean) * inv * g[c] + be[c];
        if (OUTF32) ((float*)out)[base + c] = o;
        else ((u16*)out)[base + c] = f2b(o);
    }
}

extern "C" void kernel_launch(void* const* d_in, const int* in_sizes, int n_in,
                              void* d_out, int out_size, void* d_ws, size_t ws_size,
                              hipStream_t stream) {
    const float* src = (const float*)d_in[0];
    const float* aux = (const float*)d_in[1];
    const float* Wu = (const float*)d_in[2];
    const float* bu = (const float*)d_in[3];
    const float* Wv = (const float*)d_in[4];
    const float* bv = (const float*)d_in[5];
    const float* Wo = (const float*)d_in[6];
    const float* bo = (const float*)d_in[7];
    const float* W1 = (const float*)d_in[8];
    const float* b1 = (const float*)d_in[9];
    const float* W2 = (const float*)d_in[10];
    const float* b2 = (const float*)d_in[11];
    const float* g1 = (const float*)d_in[12];
    const float* be1 = (const float*)d_in[13];
    const float* g2 = (const float*)d_in[14];
    const float* be2 = (const float*)d_in[15];
    const int* src_mask = (const int*)d_in[16];
    const int* aux_mask = (const int*)d_in[17];

    // -------- workspace (time-phased; smaller than proven R8 footprint) --------------
    char* w = (char*)d_ws;
    auto alloc = [&](size_t bytes) { char* p = w; w += (bytes + 255) & ~(size_t)255; return p; };
    // permanent (~59 MiB)
    u16* WoT = (u16*)alloc(1024L * 1024 * 2);
    u16* W1T = (u16*)alloc(4096L * 1024 * 2);
    u16* W2T = (u16*)alloc(1024L * 4096 * 2);
    u16* Vt  = (u16*)alloc(64L * 64 * 1024 * 2);
    float* RS = (float*)alloc(64L * 4096 * 4);
    u16* Qs = (u16*)alloc(64L * 1024 * 128 * 2);    // [qhi|qlo] 128-phys
    u16* Ks = (u16*)alloc(64L * 1024 * 128 * 2);    // [khi|klo] 128-phys
    // scratch union: 84 MiB, two time-phases
    char* scratch = (char*)alloc(84L * 1024 * 1024);
    // phase A: WS (split weight; later aliased by RSp after QKV gemms), As_, Uf, Vf
    u16* WS  = (u16*)(scratch);                        // 18874368
    float* RSp = (float*)(scratch);                    // 16777216 (aliases dead WS)
    u16* As_ = (u16*)(scratch + 18874368L);            // 12582912
    float* Uf = (float*)(scratch + 31457280L);         // 25165824
    float* Vf = (float*)(scratch + 56623104L);         // 25165824 (ends 81788928)
    // phase B (overlays phase-A scratch, all of which is dead by then)
    u16* ctx2   = (u16*)(scratch);                     // 8388608  [4096][1024] bf16
    u16* attn_s = (u16*)(scratch + 8388608L);          // 8388608
    u16* o1s    = (u16*)(scratch + 16777216L);         // 8388608
    u16* hbuf   = (u16*)(scratch + 25165824L);         // 33554432 [2][2048][4096]
    u16* fbuf   = (u16*)(scratch + 58720256L);         // 8388608  (ends 67108864)

    // -------- phase A: weight prep + hi/lo QKV projections + R/S + Q'/K splits ------
    transpose_cvt<<<dim3(16, 16), 256, 0, stream>>>(Wo, WoT, 1024, 1024);
    transpose_cvt<<<dim3(64, 16), 256, 0, stream>>>(W1, W1T, 1024, 4096);
    transpose_cvt<<<dim3(16, 64), 256, 0, stream>>>(W2, W2T, 4096, 1024);

    transpose_split<<<dim3(48, 16), 256, 0, stream>>>(Wu, WS, 1024, 3072);
    split_rows<<<2048, 256, 0, stream>>>(src, As_);
    gemm128<EPI_F32_BIAS, 64><<<dim3(16, 48, 1), 256, 0, stream>>>(
        As_, WS, Uf, bu, 2048, 3072, 3072, 3072, 3072, 3072, 0, 0, 0);
    transpose_split<<<dim3(48, 16), 256, 0, stream>>>(Wv, WS, 1024, 3072);
    split_rows<<<2048, 256, 0, stream>>>(aux, As_);
    gemm128<EPI_F32_BIAS, 64><<<dim3(16, 48, 1), 256, 0, stream>>>(
        As_, WS, Vf, bv, 2048, 3072, 3072, 3072, 3072, 3072, 0, 0, 0);
    // WS dead from here; RSp aliases it
    repack_vt<<<dim3(16, 64), 256, 0, stream>>>(Uf, Vf, Vt);
    rs_part<<<dim3(64, 16), 256, 0, stream>>>(Uf, Vf, src_mask, aux_mask, RSp);
    rs_reduce<<<256, 256, 0, stream>>>(RSp, RS);
    qprime<<<dim3(8, 64), 256, 0, stream>>>(Uf, Vf, RS, Qs);
    ksplit<<<dim3(16, 64), 256, 0, stream>>>(Uf, Vf, src_mask, aux_mask, Ks);
    // ---- phase A scratch (WS/RSp/As_/Uf/Vf) dead; phase B overlays ------------------

    // fused comb + softmax + PV for all 64 (s,b,h) slices in one launch
    flash_comb<<<dim3(64, 8), 512, 0, stream>>>(Qs, Ks, Vt, ctx2);

    // -------- phase B: dual-stream batched (z = stream) ------------------------------
    gemm128<EPI_BF16_BIAS, 64><<<dim3(16, 16, 2), 256, 0, stream>>>(
        ctx2, WoT, attn_s, bo, 2048, 1024, 1024, 1024, 1024, 1024,
        2048L * 1024, 0, 2048L * 1024);
    ln_fused2<true, false><<<4096, 256, 0, stream>>>(src, aux, attn_s, g1, be1, o1s);
    gemm128<EPI_BF16_BIAS_RELU, 128><<<dim3(16, 32, 2), 256, 0, stream>>>(
        o1s, W1T, hbuf, b1, 2048, 4096, 1024, 1024, 1024, 4096,
        2048L * 1024, 0, 2048L * 4096);
    gemm128<EPI_BF16_BIAS, 64><<<dim3(16, 16, 2), 256, 0, stream>>>(
        hbuf, W2T, fbuf, b2, 2048, 1024, 4096, 4096, 4096, 1024,
        2048L * 4096, 0, 2048L * 1024);
    ln_fused2<false, true><<<4096, 256, 0, stream>>>(o1s, o1s + 2048L * 1024, fbuf,
                                                     g2, be2, (float*)d_out);
}

// Round 9
// 540.933 us; speedup vs baseline: 1.1257x; 1.1257x over previous
//
#include <hip/hip_runtime.h>
#include <stdint.h>

typedef unsigned short u16;
typedef __attribute__((ext_vector_type(4))) float f32x4;
typedef __attribute__((ext_vector_type(8))) __bf16 bf16x8;
typedef __attribute__((ext_vector_type(8))) unsigned short u16x8;

#define T_ 1024
#define D_ 1024
#define HD_ 64

__device__ __forceinline__ float b2f(u16 u) {
    union { unsigned int i; float f; } x; x.i = ((unsigned int)u) << 16; return x.f;
}
__device__ __forceinline__ u16 f2b(float f) {
    union { float f; unsigned int i; } x; x.f = f;
    unsigned int i = x.i;
    unsigned int r = (i >> 16) & 1;
    i += 0x7fffu + r;
    return (u16)(i >> 16);
}

// async global->LDS, 16B per lane; LDS dest is wave-uniform base + lane*16
__device__ __forceinline__ void gl2lds16(const void* g, void* l) {
    auto gp = (const __attribute__((address_space(1))) unsigned int*)(unsigned long long)(g);
    auto lp = (__attribute__((address_space(3))) unsigned int*)(unsigned int)(unsigned long long)(l);
    __builtin_amdgcn_global_load_lds(gp, lp, 16, 0, 0);
}

__device__ __forceinline__ float wred_sum(float v) {
    #pragma unroll
    for (int o = 32; o > 0; o >>= 1) v += __shfl_down(v, o, 64);
    return v;
}
__device__ __forceinline__ float shx(float v, int m) { return __shfl_xor(v, m, 64); }

// ---------------- f32 transpose + bf16 convert: out[c*R + r] = bf16(in[r*C + c]) ----
__global__ __launch_bounds__(256) void transpose_cvt(const float* __restrict__ in,
                                                     u16* __restrict__ out, int R, int C) {
    __shared__ float Ts[64][65];
    int c0 = blockIdx.x * 64, r0 = blockIdx.y * 64;
    int tid = threadIdx.x, tx = tid & 63, ty = tid >> 6;
    #pragma unroll
    for (int i = ty; i < 64; i += 4) Ts[i][tx] = in[(long)(r0 + i) * C + c0 + tx];
    __syncthreads();
    #pragma unroll
    for (int i = ty; i < 64; i += 4)
        out[(long)(c0 + i) * R + r0 + tx] = f2b(Ts[tx][i]);
}

// ---- f32 transpose + hi/lo split: W[R,C] -> out[C, 3R] = [hi | hi | lo] ------------
__global__ __launch_bounds__(256) void transpose_split(const float* __restrict__ in,
                                                       u16* __restrict__ out, int R, int C) {
    __shared__ float Ts[64][65];
    int c0 = blockIdx.x * 64, r0 = blockIdx.y * 64;
    int tid = threadIdx.x, tx = tid & 63, ty = tid >> 6;
    #pragma unroll
    for (int i = ty; i < 64; i += 4) Ts[i][tx] = in[(long)(r0 + i) * C + c0 + tx];
    __syncthreads();
    #pragma unroll
    for (int i = ty; i < 64; i += 4) {
        float v = Ts[tx][i];
        u16 hi = f2b(v);
        u16 lo = f2b(v - b2f(hi));
        long base = (long)(c0 + i) * (3 * R) + r0 + tx;
        out[base] = hi;
        out[base + R] = hi;
        out[base + 2 * R] = lo;
    }
}

// ---- f32 rowwise hi/lo split: X[M,1024] -> out[M, 3072] = [hi | lo | hi] -----------
__global__ __launch_bounds__(256) void split_rows(const float* __restrict__ in,
                                                  u16* __restrict__ out) {
    long row = blockIdx.x;
    int tid = threadIdx.x;
    #pragma unroll
    for (int k = 0; k < 4; k++) {
        int c = tid + k * 256;
        float v = in[row * 1024 + c];
        u16 hi = f2b(v);
        u16 lo = f2b(v - b2f(hi));
        out[row * 3072 + c] = hi;
        out[row * 3072 + 1024 + c] = lo;
        out[row * 3072 + 2048 + c] = hi;
    }
}

// ------- m97-style BT GEMM, 1-barrier prefetch pipeline, z-batched ------------------
enum { EPI_F32_BIAS = 0, EPI_BF16_BIAS = 1, EPI_BF16_BIAS_RELU = 2 };

template <int EPI, int BN>
__global__ __launch_bounds__(256) void gemm128(
    const u16* __restrict__ A, const u16* __restrict__ B, void* __restrict__ C,
    const float* __restrict__ bias,
    int M, int N, int K, int lda, int ldb, int ldc,
    long sAz, long sBz, long sCz) {
    __shared__ u16 As[2][128 * 32];
    __shared__ u16 Bs[2][BN * 32];
    const int tid = threadIdx.x, wave = tid >> 6, lane = tid & 63;
    const int m0 = blockIdx.x * 128, n0 = blockIdx.y * BN;
    const int z = blockIdx.z;
    const u16* Ab = A + (long)z * sAz;
    const u16* Bb = B + (long)z * sBz;
    const int srow = lane >> 2, scol = (lane & 3) * 8;
    constexpr int IT = (BN == 128) ? 4 : 2;
    f32x4 acc[IT][4];
    #pragma unroll
    for (int i = 0; i < IT; i++)
        #pragma unroll
        for (int j = 0; j < 4; j++) acc[i][j] = (f32x4){0.f, 0.f, 0.f, 0.f};
    const int wm = (BN == 128) ? (wave >> 1) * 64 : wave * 32;
    const int wn = (BN == 128) ? (wave & 1) * 64 : 0;
    const int fr = lane & 15, fk = (lane >> 4) * 8;

    // prologue: stage k0=0 into buf 0
    {
        #pragma unroll
        for (int t = 0; t < 2; t++) {
            int rb = wave * 32 + t * 16;
            gl2lds16(Ab + (long)(m0 + rb + srow) * lda + scol, &As[0][rb * 32]);
        }
        if constexpr (BN == 128) {
            #pragma unroll
            for (int t = 0; t < 2; t++) {
                int rb = wave * 32 + t * 16;
                gl2lds16(Bb + (long)(n0 + rb + srow) * ldb + scol, &Bs[0][rb * 32]);
            }
        } else {
            int rb = wave * 16;
            gl2lds16(Bb + (long)(n0 + rb + srow) * ldb + scol, &Bs[0][rb * 32]);
        }
    }
    __syncthreads();

    for (int k0 = 0; k0 < K; k0 += 32) {
        const int buf = (k0 >> 5) & 1;
        const int kn = k0 + 32;
        if (kn < K) {   // prefetch next tile into buf^1 (overlaps with compute below)
            #pragma unroll
            for (int t = 0; t < 2; t++) {
                int rb = wave * 32 + t * 16;
                gl2lds16(Ab + (long)(m0 + rb + srow) * lda + kn + scol, &As[buf ^ 1][rb * 32]);
            }
            if constexpr (BN == 128) {
                #pragma unroll
                for (int t = 0; t < 2; t++) {
                    int rb = wave * 32 + t * 16;
                    gl2lds16(Bb + (long)(n0 + rb + srow) * ldb + kn + scol, &Bs[buf ^ 1][rb * 32]);
                }
            } else {
                int rb = wave * 16;
                gl2lds16(Bb + (long)(n0 + rb + srow) * ldb + kn + scol, &Bs[buf ^ 1][rb * 32]);
            }
        }
        bf16x8 af[IT], bv[4];
        #pragma unroll
        for (int i = 0; i < IT; i++) af[i] = *(const bf16x8*)&As[buf][(wm + i * 16 + fr) * 32 + fk];
        #pragma unroll
        for (int j = 0; j < 4; j++) bv[j] = *(const bf16x8*)&Bs[buf][(wn + j * 16 + fr) * 32 + fk];
        #pragma unroll
        for (int i = 0; i < IT; i++)
            #pragma unroll
            for (int j = 0; j < 4; j++)
                acc[i][j] = __builtin_amdgcn_mfma_f32_16x16x32_bf16(af[i], bv[j], acc[i][j], 0, 0, 0);
        __syncthreads();   // drains prefetch vmcnt (overlapped) + guards buf reuse
    }
    const int er = (lane >> 4) * 4, ec = lane & 15;
    #pragma unroll
    for (int i = 0; i < IT; i++)
        #pragma unroll
        for (int j = 0; j < 4; j++)
            #pragma unroll
            for (int r = 0; r < 4; r++) {
                const int gm = m0 + wm + i * 16 + er + r;
                const int gn = n0 + wn + j * 16 + ec;
                const float v = acc[i][j][r];
                if constexpr (EPI == EPI_F32_BIAS) {
                    ((float*)C)[(long)z * sCz + (long)gm * ldc + gn] = v + bias[gn];
                } else if constexpr (EPI == EPI_BF16_BIAS) {
                    ((u16*)C)[(long)z * sCz + (long)gm * ldc + gn] = f2b(v + bias[gn]);
                } else {
                    ((u16*)C)[(long)z * sCz + (long)gm * ldc + gn] = f2b(fmaxf(v + bias[gn], 0.0f));
                }
            }
}

// ---------------- repack V^T: Vt[s,z,d,t] = U/Vf[b*T+t, 2048+h*64+d] ----------------
__global__ __launch_bounds__(256) void repack_vt(const float* __restrict__ Uf,
                                                 const float* __restrict__ Vf,
                                                 u16* __restrict__ Vt) {
    __shared__ u16 Ts[64][65];
    int tid = threadIdx.x, tx = tid & 63, ty = tid >> 6;
    int t0 = blockIdx.x * 64;
    int sz = blockIdx.y, s = sz >> 5, z = sz & 31, b = z >> 4, h = z & 15;
    const float* srcp = s ? Vf : Uf;
    #pragma unroll
    for (int i = ty; i < 64; i += 4)
        Ts[i][tx] = f2b(srcp[(long)(b * T_ + t0 + i) * 3072 + 2048 + h * 64 + tx]);
    __syncthreads();
    u16* dst = Vt + (long)sz * HD_ * T_;
    #pragma unroll
    for (int i = ty; i < 64; i += 4) dst[(long)i * T_ + t0 + tx] = Ts[tx][i];
}

// ---- R/S partials: RSp[chunk][idx][d1*64+d2] = sum_{j in chunk} mask*k[j,d1]*q[j,d2]
__global__ __launch_bounds__(256) void rs_part(const float* __restrict__ Uf,
                                               const float* __restrict__ Vf,
                                               const int* __restrict__ smask,
                                               const int* __restrict__ amask,
                                               float* __restrict__ RSp) {
    __shared__ float Ksh[64 * 64];
    __shared__ float Qsh[64 * 64];
    int idx = blockIdx.x;
    int mat = idx >> 5, z = idx & 31, b = z >> 4, h = z & 15;
    int chunk = blockIdx.y, j0 = chunk * 64;
    const float* base = mat ? Uf : Vf;
    const int* mk = mat ? smask : amask;
    int tid = threadIdx.x;
    float4* K4 = (float4*)Ksh;
    float4* Q4 = (float4*)Qsh;
    for (int ii = tid; ii < 1024; ii += 256) {
        int j = ii >> 4, d4 = ii & 15;
        long row = (long)(b * T_ + j0 + j) * 3072 + h * 64;
        int m = mk[b * T_ + j0 + j];
        float4 kv = ((const float4*)&base[row + 1024])[d4];
        if (m <= 0) kv = (float4){0.f, 0.f, 0.f, 0.f};
        K4[ii] = kv;
        Q4[ii] = ((const float4*)&base[row])[d4];
    }
    __syncthreads();
    int d1 = tid >> 2, c0 = (tid & 3) * 16;
    float4 a[4];
    #pragma unroll
    for (int k = 0; k < 4; k++) a[k] = (float4){0.f, 0.f, 0.f, 0.f};
    for (int j = 0; j < 64; j++) {
        float kv = Ksh[j * 64 + d1];
        const float4* q = (const float4*)&Qsh[j * 64 + c0];
        #pragma unroll
        for (int k = 0; k < 4; k++) {
            float4 qv = q[k];
            a[k].x += kv * qv.x; a[k].y += kv * qv.y;
            a[k].z += kv * qv.z; a[k].w += kv * qv.w;
        }
    }
    float4* out = (float4*)&RSp[((long)chunk * 64 + idx) * 4096 + d1 * 64 + c0];
    #pragma unroll
    for (int k = 0; k < 4; k++) out[k] = a[k];
}

// ---- RS[idx][e] = sum_{chunk<16} RSp[chunk][idx][e]  (float4-wide) -----------------
__global__ __launch_bounds__(256) void rs_reduce(const float* __restrict__ RSp,
                                                 float* __restrict__ RS) {
    int gid = blockIdx.x * 256 + threadIdx.x;    // 65536 float4s
    const float4* in = (const float4*)RSp;
    float4 s = (float4){0.f, 0.f, 0.f, 0.f};
    #pragma unroll
    for (int c = 0; c < 16; c++) {
        float4 v = in[(long)c * 65536 + gid];
        s.x += v.x; s.y += v.y; s.z += v.z; s.w += v.w;
    }
    ((float4*)RS)[gid] = s;
}

// ---------------- Q' = (Q @ R)/64, hi/lo split to [qhi|qlo] (128) -------------------
__global__ __launch_bounds__(256) void qprime(const float* __restrict__ Uf,
                                              const float* __restrict__ Vf,
                                              const float* __restrict__ RS,
                                              u16* __restrict__ Qs) {
    __shared__ float Rm[4096];
    __shared__ float Qsh[128][65];
    int t0 = blockIdx.x * 128;
    int sz = blockIdx.y, s = sz >> 5, z = sz & 31, b = z >> 4, h = z & 15;
    const float* Qf = s ? Vf : Uf;
    const float* mat = RS + (long)(s * 32 + z) * 4096;
    int tid = threadIdx.x;
    for (int ii = tid; ii < 1024; ii += 256)
        ((float4*)Rm)[ii] = ((const float4*)mat)[ii];
    for (int ii = tid; ii < 2048; ii += 256) {
        int j = ii >> 4, d4 = ii & 15;
        float4 v = ((const float4*)&Qf[(long)(b * T_ + t0 + j) * 3072 + h * 64])[d4];
        Qsh[j][d4 * 4] = v.x; Qsh[j][d4 * 4 + 1] = v.y;
        Qsh[j][d4 * 4 + 2] = v.z; Qsh[j][d4 * 4 + 3] = v.w;
    }
    __syncthreads();
    int r = tid >> 1, c0 = (tid & 1) * 32;
    float4 acc[8];
    #pragma unroll
    for (int k = 0; k < 8; k++) acc[k] = (float4){0.f, 0.f, 0.f, 0.f};
    for (int d1 = 0; d1 < 64; d1++) {
        float q = Qsh[r][d1];
        const float4* rm = (const float4*)&Rm[d1 * 64 + c0];
        #pragma unroll
        for (int k = 0; k < 8; k++) {
            float4 rv = rm[k];
            acc[k].x += q * rv.x; acc[k].y += q * rv.y;
            acc[k].z += q * rv.z; acc[k].w += q * rv.w;
        }
    }
    u16 hiA[32], loA[32];
    #pragma unroll
    for (int k = 0; k < 8; k++) {
        #pragma unroll
        for (int e = 0; e < 4; e++) {
            float x = ((const float*)&acc[k])[e] * (1.f / 64.f);
            int c = k * 4 + e;
            u16 hi = f2b(x);
            hiA[c] = hi;
            loA[c] = f2b(x - b2f(hi));
        }
    }
    u16* out = Qs + ((long)sz * T_ + (t0 + r)) * 128;
    #pragma unroll
    for (int i = 0; i < 4; i++) {
        *(u16x8*)&out[c0 + i * 8]      = *(const u16x8*)&hiA[i * 8];
        *(u16x8*)&out[64 + c0 + i * 8] = *(const u16x8*)&loA[i * 8];
    }
}

// ---------------- K split to [khi|klo] (128), masked rows zeroed --------------------
__global__ __launch_bounds__(256) void ksplit(const float* __restrict__ Uf,
                                              const float* __restrict__ Vf,
                                              const int* __restrict__ src_mask,
                                              const int* __restrict__ aux_mask,
                                              u16* __restrict__ Ks) {
    int t0 = blockIdx.x * 64;
    int sz = blockIdx.y, s = sz >> 5, z = sz & 31, b = z >> 4, h = z & 15;
    const float* Kf = s ? Vf : Uf;
    const int* mk = s ? aux_mask : src_mask;
    int tid = threadIdx.x;
    #pragma unroll
    for (int uu = 0; uu < 4; uu++) {
        int u = tid + uu * 256;             // 0..1023 = 64 rows x 16 16B-units
        int lr = u >> 4;
        int s16 = u & 15;                   // 0..15
        int seg = s16 >> 3;                 // 0:hi 1:lo
        int off = (s16 & 7) * 8;            // 0..56
        int r = t0 + lr;
        int m = mk[b * T_ + r];
        const float* srcp = &Kf[(long)(b * T_ + r) * 3072 + 1024 + h * 64 + off];
        float4 va = ((const float4*)srcp)[0];
        float4 vb = ((const float4*)srcp)[1];
        float xs[8] = {va.x, va.y, va.z, va.w, vb.x, vb.y, vb.z, vb.w};
        u16x8 wv;
        #pragma unroll
        for (int e = 0; e < 8; e++) {
            float x = (m > 0) ? xs[e] : 0.0f;
            u16 hi = f2b(x);
            wv[e] = (seg == 1) ? f2b(x - b2f(hi)) : hi;
        }
        *(u16x8*)&Ks[((long)sz * T_ + r) * 128 + seg * 64 + off] = wv;
    }
}

// ------- fused flash attention: logical K=192 via 128-phys hi/lo fragment reuse -----
// 512 threads (8 waves x 16 q-rows), KVBLK=64, K/V double-buffered, 64KB LDS.
// Exact R7 swizzles (measured 0 bank conflicts); only K phys width 192->128.
__global__ __launch_bounds__(512, 4) void flash_comb(const u16* __restrict__ Qs,
                                                     const u16* __restrict__ Ks,
                                                     const u16* __restrict__ Vt,
                                                     u16* __restrict__ ctx2) {
    __shared__ u16 Ksh[2][64 * 128]; // [buf][row][unit c16 ^ (row&7)], 16KB each
    __shared__ u16 Vsh[2][64 * 64];  // [buf][d][unit c16 ^ (d&7)], 8KB each
    __shared__ u16 Psh[128 * 64];    // [q][col ^ ((q&7)<<3)], 16KB (32-bank span)
    const int tid = threadIdx.x, wave = tid >> 6, lane = tid & 63;
    const int z = blockIdx.x;
    const int m0 = blockIdx.y * 128;
    const int h = z & 15;
    const int g = lane >> 4, fr = lane & 15;
    const int wm = wave * 16;
    const u16* Qb = Qs + (long)z * T_ * 128;
    const u16* Kb = Ks + (long)z * T_ * 128;
    const u16* Vb = Vt + (long)z * HD_ * T_;

    // staging: 24 1KB slots (16 K + 8 V); wave w: slots {w, w+8, w+16}
    auto STAGE = [&](int k0, int buf) {
        #pragma unroll
        for (int t = 0; t < 3; t++) {
            int slot = wave + t * 8;
            if (slot < 16) {         // K: 64 rows x 16 units
                int o16 = slot * 64 + lane;
                int row = o16 >> 4, c16 = o16 & 15;
                gl2lds16(Kb + (long)(k0 + row) * 128 + ((c16 ^ (row & 7)) * 8),
                         &Ksh[buf][slot * 512]);
            } else {                 // V: 64 d-rows x 8 units
                int o16 = (slot - 16) * 64 + lane;
                int d = o16 >> 3, c16 = o16 & 7;
                gl2lds16(Vb + (long)d * T_ + k0 + ((c16 ^ (d & 7)) * 8),
                         &Vsh[buf][(slot - 16) * 512]);
            }
        }
    };

    // Q' phys fragments (4): [qhi chunk0, qhi chunk1, qlo chunk0, qlo chunk1]
    bf16x8 qA[4];
    #pragma unroll
    for (int p = 0; p < 4; p++)
        qA[p] = *(const bf16x8*)&Qb[(long)(m0 + wm + fr) * 128 + p * 32 + g * 8];

    f32x4 oacc[4], mrun, lrun;
    mrun = (f32x4){-1e30f, -1e30f, -1e30f, -1e30f};
    lrun = (f32x4){0.f, 0.f, 0.f, 0.f};
    #pragma unroll
    for (int dj = 0; dj < 4; dj++) oacc[dj] = (f32x4){0.f, 0.f, 0.f, 0.f};

    STAGE(0, 0);
    __syncthreads();

    #pragma unroll 1
    for (int kt = 0; kt < 16; kt++) {
        const int buf = kt & 1;
        if (kt < 15) STAGE((kt + 1) * 64, buf ^ 1);   // prefetch overlaps compute

        // S = Q' K^T (16 q-rows x 64 k-cols), logical K=192 via fragment reuse:
        //   S = qhi.khi + qlo.khi + qhi.klo  (chunked over 2 MFMA k-slices each)
        f32x4 sacc[4];
        #pragma unroll
        for (int ki = 0; ki < 4; ki++) sacc[ki] = (f32x4){0.f, 0.f, 0.f, 0.f};
        __builtin_amdgcn_s_setprio(1);
        {
            bf16x8 kb[2][4];
            // khi chunks (units [0,8))
            #pragma unroll
            for (int pk = 0; pk < 2; pk++)
                #pragma unroll
                for (int ki = 0; ki < 4; ki++) {
                    int row = ki * 16 + fr;
                    kb[pk][ki] = *(const bf16x8*)&Ksh[buf][row * 128 + (((pk * 4 + g) ^ (row & 7)) * 8)];
                }
            #pragma unroll
            for (int ki = 0; ki < 4; ki++) {
                sacc[ki] = __builtin_amdgcn_mfma_f32_16x16x32_bf16(qA[0], kb[0][ki], sacc[ki], 0, 0, 0);
                sacc[ki] = __builtin_amdgcn_mfma_f32_16x16x32_bf16(qA[1], kb[1][ki], sacc[ki], 0, 0, 0);
                sacc[ki] = __builtin_amdgcn_mfma_f32_16x16x32_bf16(qA[2], kb[0][ki], sacc[ki], 0, 0, 0);
                sacc[ki] = __builtin_amdgcn_mfma_f32_16x16x32_bf16(qA[3], kb[1][ki], sacc[ki], 0, 0, 0);
            }
            // klo chunks (units [8,16))
            #pragma unroll
            for (int pk = 0; pk < 2; pk++)
                #pragma unroll
                for (int ki = 0; ki < 4; ki++) {
                    int row = ki * 16 + fr;
                    kb[pk][ki] = *(const bf16x8*)&Ksh[buf][row * 128 + ((((pk + 2) * 4 + g) ^ (row & 7)) * 8)];
                }
            #pragma unroll
            for (int ki = 0; ki < 4; ki++) {
                sacc[ki] = __builtin_amdgcn_mfma_f32_16x16x32_bf16(qA[0], kb[0][ki], sacc[ki], 0, 0, 0);
                sacc[ki] = __builtin_amdgcn_mfma_f32_16x16x32_bf16(qA[1], kb[1][ki], sacc[ki], 0, 0, 0);
            }
        }
        __builtin_amdgcn_s_setprio(0);

        // online softmax in C-layout: row = wm + g*4+e, col = ki*16+fr; tree max
        f32x4 tm;
        #pragma unroll
        for (int e = 0; e < 4; e++)
            tm[e] = fmaxf(fmaxf(sacc[0][e], sacc[1][e]), fmaxf(sacc[2][e], sacc[3][e]));
        #pragma unroll
        for (int off = 1; off < 16; off <<= 1)
            #pragma unroll
            for (int e = 0; e < 4; e++) tm[e] = fmaxf(tm[e], shx(tm[e], off));

        // defer-max (T13): only rescale when tile max grew past mrun + 8
        int within = (tm[0] <= mrun[0] + 8.f) && (tm[1] <= mrun[1] + 8.f) &&
                     (tm[2] <= mrun[2] + 8.f) && (tm[3] <= mrun[3] + 8.f);
        if (!__all(within)) {
            f32x4 alpha;
            #pragma unroll
            for (int e = 0; e < 4; e++) {
                float mnew = fmaxf(mrun[e], tm[e]);
                alpha[e] = __expf(mrun[e] - mnew);
                mrun[e] = mnew;
            }
            #pragma unroll
            for (int dj = 0; dj < 4; dj++)
                #pragma unroll
                for (int e = 0; e < 4; e++) oacc[dj][e] *= alpha[e];
            #pragma unroll
            for (int e = 0; e < 4; e++) lrun[e] *= alpha[e];
        }

        f32x4 psum = (f32x4){0.f, 0.f, 0.f, 0.f};
        #pragma unroll
        for (int ki = 0; ki < 4; ki++) {
            #pragma unroll
            for (int e = 0; e < 4; e++) {
                float p = __expf(sacc[ki][e] - mrun[e]);
                psum[e] += p;
                int row = wm + g * 4 + e;
                Psh[row * 64 + ((ki * 16 + fr) ^ ((row & 7) << 3))] = f2b(p);
            }
        }
        #pragma unroll
        for (int off = 1; off < 16; off <<= 1)
            #pragma unroll
            for (int e = 0; e < 4; e++) psum[e] += shx(psum[e], off);
        #pragma unroll
        for (int e = 0; e < 4; e++) lrun[e] += psum[e];

        // PV: O += P @ V (P via LDS round-trip C-layout -> A-layout, wave-private)
        bf16x8 pa[2];
        #pragma unroll
        for (int ks = 0; ks < 2; ks++) {
            int row = wm + fr;
            pa[ks] = *(const bf16x8*)&Psh[row * 64 + (((ks * 4 + g) ^ (row & 7)) * 8)];
        }
        __builtin_amdgcn_s_setprio(1);
        #pragma unroll
        for (int dj = 0; dj < 4; dj++) {
            int d = dj * 16 + fr;
            bf16x8 vb0 = *(const bf16x8*)&Vsh[buf][d * 64 + (((0 * 4 + g) ^ (d & 7)) * 8)];
            bf16x8 vb1 = *(const bf16x8*)&Vsh[buf][d * 64 + (((1 * 4 + g) ^ (d & 7)) * 8)];
            oacc[dj] = __builtin_amdgcn_mfma_f32_16x16x32_bf16(pa[0], vb0, oacc[dj], 0, 0, 0);
            oacc[dj] = __builtin_amdgcn_mfma_f32_16x16x32_bf16(pa[1], vb1, oacc[dj], 0, 0, 0);
        }
        __builtin_amdgcn_s_setprio(0);
        __syncthreads();   // drains prefetch vmcnt (overlapped) + guards buf reuse
    }

    // epilogue: O /= l; ctx2 flat [4096][1024], row = (z>>4)*T + qr
    f32x4 inv;
    #pragma unroll
    for (int e = 0; e < 4; e++) inv[e] = 1.f / lrun[e];
    #pragma unroll
    for (int dj = 0; dj < 4; dj++)
        #pragma unroll
        for (int e = 0; e < 4; e++) {
            int qr = m0 + wm + g * 4 + e;
            int dc = dj * 16 + fr;
            ctx2[((long)((z >> 4) * T_ + qr)) * D_ + h * 64 + dc] = f2b(oacc[dj][e] * inv[e]);
        }
}

// ------- fused residual-add + LayerNorm, dual-stream batched (4096 rows) ------------
template <bool XF32, bool OUTF32>
__global__ __launch_bounds__(256) void ln_fused2(const void* __restrict__ x0,
                                                 const void* __restrict__ x1,
                                                 const u16* __restrict__ y,
                                                 const float* __restrict__ g,
                                                 const float* __restrict__ be,
                                                 void* __restrict__ out) {
    __shared__ float red[8];
    int row = blockIdx.x;
    const void* xp = (row < 2048) ? x0 : x1;
    long xbase = (long)((row < 2048) ? row : row - 2048) * 1024;
    long base = (long)row * 1024;
    int tid = threadIdx.x, wave = tid >> 6, lane = tid & 63;
    float v[4];
    #pragma unroll
    for (int i = 0; i < 4; i++) {
        int c = tid + i * 256;
        float xv = XF32 ? ((const float*)xp)[xbase + c] : b2f(((const u16*)xp)[xbase + c]);
        v[i] = xv + b2f(y[base + c]);
    }
    float s = v[0] + v[1] + v[2] + v[3];
    float q = v[0] * v[0] + v[1] * v[1] + v[2] * v[2] + v[3] * v[3];
    s = wred_sum(s);
    q = wred_sum(q);
    if (lane == 0) { red[wave] = s; red[4 + wave] = q; }
    __syncthreads();
    s = red[0] + red[1] + red[2] + red[3];
    q = red[4] + red[5] + red[6] + red[7];
    float mean = s * (1.f / 1024.f);
    float var = q * (1.f / 1024.f) - mean * mean;
    float inv = rsqrtf(var + 1e-5f);
    #pragma unroll
    for (int i = 0; i < 4; i++) {
        int c = tid + i * 256;
        float o = (v[i] - mean) * inv * g[c] + be[c];
        if (OUTF32) ((float*)out)[base + c] = o;
        else ((u16*)out)[base + c] = f2b(o);
    }
}

extern "C" void kernel_launch(void* const* d_in, const int* in_sizes, int n_in,
                              void* d_out, int out_size, void* d_ws, size_t ws_size,
                              hipStream_t stream) {
    const float* src = (const float*)d_in[0];
    const float* aux = (const float*)d_in[1];
    const float* Wu = (const float*)d_in[2];
    const float* bu = (const float*)d_in[3];
    const float* Wv = (const float*)d_in[4];
    const float* bv = (const float*)d_in[5];
    const float* Wo = (const float*)d_in[6];
    const float* bo = (const float*)d_in[7];
    const float* W1 = (const float*)d_in[8];
    const float* b1 = (const float*)d_in[9];
    const float* W2 = (const float*)d_in[10];
    const float* b2 = (const float*)d_in[11];
    const float* g1 = (const float*)d_in[12];
    const float* be1 = (const float*)d_in[13];
    const float* g2 = (const float*)d_in[14];
    const float* be2 = (const float*)d_in[15];
    const int* src_mask = (const int*)d_in[16];
    const int* aux_mask = (const int*)d_in[17];

    // -------- workspace (time-phased; ~143 MiB peak) ---------------------------------
    char* w = (char*)d_ws;
    auto alloc = [&](size_t bytes) { char* p = w; w += (bytes + 255) & ~(size_t)255; return p; };
    // permanent (~59 MiB)
    u16* WoT = (u16*)alloc(1024L * 1024 * 2);
    u16* W1T = (u16*)alloc(4096L * 1024 * 2);
    u16* W2T = (u16*)alloc(1024L * 4096 * 2);
    u16* Vt  = (u16*)alloc(64L * 64 * 1024 * 2);
    float* RS = (float*)alloc(64L * 4096 * 4);
    u16* Qs = (u16*)alloc(64L * 1024 * 128 * 2);    // [qhi|qlo] 128-phys
    u16* Ks = (u16*)alloc(64L * 1024 * 128 * 2);    // [khi|klo] 128-phys
    // scratch union: 84 MiB, two time-phases
    char* scratch = (char*)alloc(84L * 1024 * 1024);
    // phase A: WS (split weight; later aliased by RSp after QKV gemms), As_, Uf, Vf
    u16* WS  = (u16*)(scratch);                        // 18874368
    float* RSp = (float*)(scratch);                    // 16777216 (aliases dead WS)
    u16* As_ = (u16*)(scratch + 18874368L);            // 12582912
    float* Uf = (float*)(scratch + 31457280L);         // 25165824
    float* Vf = (float*)(scratch + 56623104L);         // 25165824 (ends 81788928)
    // phase B (overlays phase-A scratch, all of which is dead by then)
    u16* ctx2   = (u16*)(scratch);                     // 8388608  [4096][1024] bf16
    u16* attn_s = (u16*)(scratch + 8388608L);          // 8388608
    u16* o1s    = (u16*)(scratch + 16777216L);         // 8388608
    u16* hbuf   = (u16*)(scratch + 25165824L);         // 33554432 [2][2048][4096]
    u16* fbuf   = (u16*)(scratch + 58720256L);         // 8388608  (ends 67108864)

    // -------- phase A: weight prep + hi/lo QKV projections + R/S + Q'/K splits ------
    transpose_cvt<<<dim3(16, 16), 256, 0, stream>>>(Wo, WoT, 1024, 1024);
    transpose_cvt<<<dim3(64, 16), 256, 0, stream>>>(W1, W1T, 1024, 4096);
    transpose_cvt<<<dim3(16, 64), 256, 0, stream>>>(W2, W2T, 4096, 1024);

    transpose_split<<<dim3(48, 16), 256, 0, stream>>>(Wu, WS, 1024, 3072);
    split_rows<<<2048, 256, 0, stream>>>(src, As_);
    gemm128<EPI_F32_BIAS, 128><<<dim3(16, 24, 1), 256, 0, stream>>>(
        As_, WS, Uf, bu, 2048, 3072, 3072, 3072, 3072, 3072, 0, 0, 0);
    transpose_split<<<dim3(48, 16), 256, 0, stream>>>(Wv, WS, 1024, 3072);
    split_rows<<<2048, 256, 0, stream>>>(aux, As_);
    gemm128<EPI_F32_BIAS, 128><<<dim3(16, 24, 1), 256, 0, stream>>>(
        As_, WS, Vf, bv, 2048, 3072, 3072, 3072, 3072, 3072, 0, 0, 0);
    // WS dead from here; RSp aliases it
    repack_vt<<<dim3(16, 64), 256, 0, stream>>>(Uf, Vf, Vt);
    rs_part<<<dim3(64, 16), 256, 0, stream>>>(Uf, Vf, src_mask, aux_mask, RSp);
    rs_reduce<<<256, 256, 0, stream>>>(RSp, RS);
    qprime<<<dim3(8, 64), 256, 0, stream>>>(Uf, Vf, RS, Qs);
    ksplit<<<dim3(16, 64), 256, 0, stream>>>(Uf, Vf, src_mask, aux_mask, Ks);
    // ---- phase A scratch (WS/RSp/As_/Uf/Vf) dead; phase B overlays ------------------

    // fused comb + softmax + PV for all 64 (s,b,h) slices in one launch
    flash_comb<<<dim3(64, 8), 512, 0, stream>>>(Qs, Ks, Vt, ctx2);

    // -------- phase B: dual-stream batched (z = stream) ------------------------------
    gemm128<EPI_BF16_BIAS, 64><<<dim3(16, 16, 2), 256, 0, stream>>>(
        ctx2, WoT, attn_s, bo, 2048, 1024, 1024, 1024, 1024, 1024,
        2048L * 1024, 0, 2048L * 1024);
    ln_fused2<true, false><<<4096, 256, 0, stream>>>(src, aux, attn_s, g1, be1, o1s);
    gemm128<EPI_BF16_BIAS_RELU, 128><<<dim3(16, 32, 2), 256, 0, stream>>>(
        o1s, W1T, hbuf, b1, 2048, 4096, 1024, 1024, 1024, 4096,
        2048L * 1024, 0, 2048L * 4096);
    gemm128<EPI_BF16_BIAS, 64><<<dim3(16, 16, 2), 256, 0, stream>>>(
        hbuf, W2T, fbuf, b2, 2048, 1024, 4096, 4096, 4096, 1024,
        2048L * 4096, 0, 2048L * 1024);
    ln_fused2<false, true><<<4096, 256, 0, stream>>>(o1s, o1s + 2048L * 1024, fbuf,
                                                     g2, be2, (float*)d_out);
}

// Round 10
// 508.595 us; speedup vs baseline: 1.1973x; 1.0636x over previous
//
#include <hip/hip_runtime.h>
#include <stdint.h>

typedef unsigned short u16;
typedef __attribute__((ext_vector_type(4))) float f32x4;
typedef __attribute__((ext_vector_type(8))) __bf16 bf16x8;
typedef __attribute__((ext_vector_type(8))) unsigned short u16x8;

#define T_ 1024
#define D_ 1024
#define HD_ 64

__device__ __forceinline__ float b2f(u16 u) {
    union { unsigned int i; float f; } x; x.i = ((unsigned int)u) << 16; return x.f;
}
__device__ __forceinline__ u16 f2b(float f) {
    union { float f; unsigned int i; } x; x.f = f;
    unsigned int i = x.i;
    unsigned int r = (i >> 16) & 1;
    i += 0x7fffu + r;
    return (u16)(i >> 16);
}

// async global->LDS, 16B per lane; LDS dest is wave-uniform base + lane*16
__device__ __forceinline__ void gl2lds16(const void* g, void* l) {
    auto gp = (const __attribute__((address_space(1))) unsigned int*)(unsigned long long)(g);
    auto lp = (__attribute__((address_space(3))) unsigned int*)(unsigned int)(unsigned long long)(l);
    __builtin_amdgcn_global_load_lds(gp, lp, 16, 0, 0);
}

__device__ __forceinline__ float wred_sum(float v) {
    #pragma unroll
    for (int o = 32; o > 0; o >>= 1) v += __shfl_down(v, o, 64);
    return v;
}
__device__ __forceinline__ float shx(float v, int m) { return __shfl_xor(v, m, 64); }

// ---------------- f32 transpose + bf16 convert: out[c*R + r] = bf16(in[r*C + c]) ----
__global__ __launch_bounds__(256) void transpose_cvt(const float* __restrict__ in,
                                                     u16* __restrict__ out, int R, int C) {
    __shared__ float Ts[64][65];
    int c0 = blockIdx.x * 64, r0 = blockIdx.y * 64;
    int tid = threadIdx.x, tx = tid & 63, ty = tid >> 6;
    #pragma unroll
    for (int i = ty; i < 64; i += 4) Ts[i][tx] = in[(long)(r0 + i) * C + c0 + tx];
    __syncthreads();
    #pragma unroll
    for (int i = ty; i < 64; i += 4)
        out[(long)(c0 + i) * R + r0 + tx] = f2b(Ts[tx][i]);
}

// ---- f32 transpose + hi/lo split: W[R,C] -> out[C, 2R] = [hi | lo] -----------------
__global__ __launch_bounds__(256) void wsplit2(const float* __restrict__ in,
                                               u16* __restrict__ out, int R, int C) {
    __shared__ float Ts[64][65];
    int c0 = blockIdx.x * 64, r0 = blockIdx.y * 64;
    int tid = threadIdx.x, tx = tid & 63, ty = tid >> 6;
    #pragma unroll
    for (int i = ty; i < 64; i += 4) Ts[i][tx] = in[(long)(r0 + i) * C + c0 + tx];
    __syncthreads();
    #pragma unroll
    for (int i = ty; i < 64; i += 4) {
        float v = Ts[tx][i];
        u16 hi = f2b(v);
        u16 lo = f2b(v - b2f(hi));
        long base = (long)(c0 + i) * (2 * R) + r0 + tx;
        out[base] = hi;
        out[base + R] = lo;
    }
}

// ---- f32 rowwise hi/lo split: X[M,1024] -> out[M, 2048] = [hi | lo], z-batched -----
__global__ __launch_bounds__(256) void split2(const float* __restrict__ x0,
                                              const float* __restrict__ x1,
                                              u16* __restrict__ out) {
    long row = blockIdx.x;
    int z = blockIdx.y;
    const float* in = z ? x1 : x0;
    u16* o = out + (long)z * 2048 * 2048;
    int tid = threadIdx.x;
    #pragma unroll
    for (int k = 0; k < 4; k++) {
        int c = tid + k * 256;
        float v = in[row * 1024 + c];
        u16 hi = f2b(v);
        u16 lo = f2b(v - b2f(hi));
        o[row * 2048 + c] = hi;
        o[row * 2048 + 1024 + c] = lo;
    }
}

// ------- m97-style BT GEMM, 1-barrier prefetch pipeline, z-batched ------------------
enum { EPI_F32_BIAS = 0, EPI_BF16_BIAS = 1, EPI_BF16_BIAS_RELU = 2 };

template <int EPI, int BN>
__global__ __launch_bounds__(256) void gemm128(
    const u16* __restrict__ A, const u16* __restrict__ B, void* __restrict__ C,
    const float* __restrict__ bias,
    int M, int N, int K, int lda, int ldb, int ldc,
    long sAz, long sBz, long sCz) {
    __shared__ u16 As[2][128 * 32];
    __shared__ u16 Bs[2][BN * 32];
    const int tid = threadIdx.x, wave = tid >> 6, lane = tid & 63;
    const int m0 = blockIdx.x * 128, n0 = blockIdx.y * BN;
    const int z = blockIdx.z;
    const u16* Ab = A + (long)z * sAz;
    const u16* Bb = B + (long)z * sBz;
    const int srow = lane >> 2, scol = (lane & 3) * 8;
    constexpr int IT = (BN == 128) ? 4 : 2;
    f32x4 acc[IT][4];
    #pragma unroll
    for (int i = 0; i < IT; i++)
        #pragma unroll
        for (int j = 0; j < 4; j++) acc[i][j] = (f32x4){0.f, 0.f, 0.f, 0.f};
    const int wm = (BN == 128) ? (wave >> 1) * 64 : wave * 32;
    const int wn = (BN == 128) ? (wave & 1) * 64 : 0;
    const int fr = lane & 15, fk = (lane >> 4) * 8;

    // prologue: stage k0=0 into buf 0
    {
        #pragma unroll
        for (int t = 0; t < 2; t++) {
            int rb = wave * 32 + t * 16;
            gl2lds16(Ab + (long)(m0 + rb + srow) * lda + scol, &As[0][rb * 32]);
        }
        if constexpr (BN == 128) {
            #pragma unroll
            for (int t = 0; t < 2; t++) {
                int rb = wave * 32 + t * 16;
                gl2lds16(Bb + (long)(n0 + rb + srow) * ldb + scol, &Bs[0][rb * 32]);
            }
        } else {
            int rb = wave * 16;
            gl2lds16(Bb + (long)(n0 + rb + srow) * ldb + scol, &Bs[0][rb * 32]);
        }
    }
    __syncthreads();

    for (int k0 = 0; k0 < K; k0 += 32) {
        const int buf = (k0 >> 5) & 1;
        const int kn = k0 + 32;
        if (kn < K) {   // prefetch next tile into buf^1 (overlaps with compute below)
            #pragma unroll
            for (int t = 0; t < 2; t++) {
                int rb = wave * 32 + t * 16;
                gl2lds16(Ab + (long)(m0 + rb + srow) * lda + kn + scol, &As[buf ^ 1][rb * 32]);
            }
            if constexpr (BN == 128) {
                #pragma unroll
                for (int t = 0; t < 2; t++) {
                    int rb = wave * 32 + t * 16;
                    gl2lds16(Bb + (long)(n0 + rb + srow) * ldb + kn + scol, &Bs[buf ^ 1][rb * 32]);
                }
            } else {
                int rb = wave * 16;
                gl2lds16(Bb + (long)(n0 + rb + srow) * ldb + kn + scol, &Bs[buf ^ 1][rb * 32]);
            }
        }
        bf16x8 af[IT], bv[4];
        #pragma unroll
        for (int i = 0; i < IT; i++) af[i] = *(const bf16x8*)&As[buf][(wm + i * 16 + fr) * 32 + fk];
        #pragma unroll
        for (int j = 0; j < 4; j++) bv[j] = *(const bf16x8*)&Bs[buf][(wn + j * 16 + fr) * 32 + fk];
        #pragma unroll
        for (int i = 0; i < IT; i++)
            #pragma unroll
            for (int j = 0; j < 4; j++)
                acc[i][j] = __builtin_amdgcn_mfma_f32_16x16x32_bf16(af[i], bv[j], acc[i][j], 0, 0, 0);
        __syncthreads();   // drains prefetch vmcnt (overlapped) + guards buf reuse
    }
    const int er = (lane >> 4) * 4, ec = lane & 15;
    #pragma unroll
    for (int i = 0; i < IT; i++)
        #pragma unroll
        for (int j = 0; j < 4; j++)
            #pragma unroll
            for (int r = 0; r < 4; r++) {
                const int gm = m0 + wm + i * 16 + er + r;
                const int gn = n0 + wn + j * 16 + ec;
                const float v = acc[i][j][r];
                if constexpr (EPI == EPI_F32_BIAS) {
                    ((float*)C)[(long)z * sCz + (long)gm * ldc + gn] = v + bias[gn];
                } else if constexpr (EPI == EPI_BF16_BIAS) {
                    ((u16*)C)[(long)z * sCz + (long)gm * ldc + gn] = f2b(v + bias[gn]);
                } else {
                    ((u16*)C)[(long)z * sCz + (long)gm * ldc + gn] = f2b(fmaxf(v + bias[gn], 0.0f));
                }
            }
}

// ------- QKV GEMM with hi/lo fragment reuse: C = xhi.whi + xlo.whi + xhi.wlo --------
// A[M, 2048] = [xhi|xlo], B[N, 2048] = [whi|wlo] (both hi/lo halves of logical K=1024).
// 128x128 tile, 48 MFMA per 32-k step (3x density of gemm128), z = stream (bias sel).
__global__ __launch_bounds__(256) void gemm_hl(
    const u16* __restrict__ A, const u16* __restrict__ B, float* __restrict__ C,
    const float* __restrict__ bias0, const float* __restrict__ bias1,
    long sAz, long sBz, long sCz) {
    __shared__ u16 As[2][128 * 64];   // [buf][row][8 units; phys = l ^ (row&7)]
    __shared__ u16 Bs[2][128 * 64];
    const int tid = threadIdx.x, wave = tid >> 6, lane = tid & 63;
    const int m0 = blockIdx.x * 128, n0 = blockIdx.y * 128;
    const int z = blockIdx.z;
    const u16* Ab = A + (long)z * sAz;
    const u16* Bb = B + (long)z * sBz;
    const float* bp = z ? bias1 : bias0;
    const int fr = lane & 15, g = lane >> 4;
    const int wm = (wave >> 1) * 64, wn = (wave & 1) * 64;
    f32x4 acc[4][4];
    #pragma unroll
    for (int i = 0; i < 4; i++)
        #pragma unroll
        for (int j = 0; j < 4; j++) acc[i][j] = (f32x4){0.f, 0.f, 0.f, 0.f};

    // 32 slots (16 A + 16 B), 1KB each; wave owns 8. Linear LDS dest; source col is
    // inverse-swizzled so the read-side XOR (l ^ (row&7)) sees the right data.
    auto STAGE = [&](int k0, int buf) {
        #pragma unroll
        for (int t = 0; t < 8; t++) {
            int slot = wave * 8 + t;
            int o16 = (slot & 15) * 64 + lane;
            int row = o16 >> 3, p = o16 & 7;
            int l = p ^ (row & 7);
            int srccol = (l < 4) ? (k0 + l * 8) : (1024 + k0 + (l - 4) * 8);
            if (slot < 16)
                gl2lds16(Ab + (long)(m0 + row) * 2048 + srccol, &As[buf][(slot & 15) * 512]);
            else
                gl2lds16(Bb + (long)(n0 + row) * 2048 + srccol, &Bs[buf][(slot & 15) * 512]);
        }
    };

    STAGE(0, 0);
    __syncthreads();

    for (int k0 = 0; k0 < 1024; k0 += 32) {
        const int buf = (k0 >> 5) & 1;
        if (k0 + 32 < 1024) STAGE(k0 + 32, buf ^ 1);   // prefetch overlaps compute
        bf16x8 ah[4], al[4], bh[4], bl[4];
        #pragma unroll
        for (int i = 0; i < 4; i++) {
            int r = wm + i * 16 + fr;
            ah[i] = *(const bf16x8*)&As[buf][r * 64 + ((g ^ (r & 7)) * 8)];
            al[i] = *(const bf16x8*)&As[buf][r * 64 + (((4 + g) ^ (r & 7)) * 8)];
        }
        #pragma unroll
        for (int j = 0; j < 4; j++) {
            int r = wn + j * 16 + fr;
            bh[j] = *(const bf16x8*)&Bs[buf][r * 64 + ((g ^ (r & 7)) * 8)];
            bl[j] = *(const bf16x8*)&Bs[buf][r * 64 + (((4 + g) ^ (r & 7)) * 8)];
        }
        #pragma unroll
        for (int i = 0; i < 4; i++)
            #pragma unroll
            for (int j = 0; j < 4; j++) {
                acc[i][j] = __builtin_amdgcn_mfma_f32_16x16x32_bf16(ah[i], bh[j], acc[i][j], 0, 0, 0);
                acc[i][j] = __builtin_amdgcn_mfma_f32_16x16x32_bf16(al[i], bh[j], acc[i][j], 0, 0, 0);
                acc[i][j] = __builtin_amdgcn_mfma_f32_16x16x32_bf16(ah[i], bl[j], acc[i][j], 0, 0, 0);
            }
        __syncthreads();   // drains prefetch vmcnt (overlapped) + guards buf reuse
    }
    const int er = (lane >> 4) * 4, ec = lane & 15;
    #pragma unroll
    for (int i = 0; i < 4; i++)
        #pragma unroll
        for (int j = 0; j < 4; j++)
            #pragma unroll
            for (int r = 0; r < 4; r++) {
                const int gm = m0 + wm + i * 16 + er + r;
                const int gn = n0 + wn + j * 16 + ec;
                C[(long)z * sCz + (long)gm * 3072 + gn] = acc[i][j][r] + bp[gn];
            }
}

// ---------------- repack V^T: Vt[s,z,d,t] = U/Vf[b*T+t, 2048+h*64+d] ----------------
__global__ __launch_bounds__(256) void repack_vt(const float* __restrict__ Uf,
                                                 const float* __restrict__ Vf,
                                                 u16* __restrict__ Vt) {
    __shared__ u16 Ts[64][65];
    int tid = threadIdx.x, tx = tid & 63, ty = tid >> 6;
    int t0 = blockIdx.x * 64;
    int sz = blockIdx.y, s = sz >> 5, z = sz & 31, b = z >> 4, h = z & 15;
    const float* srcp = s ? Vf : Uf;
    #pragma unroll
    for (int i = ty; i < 64; i += 4)
        Ts[i][tx] = f2b(srcp[(long)(b * T_ + t0 + i) * 3072 + 2048 + h * 64 + tx]);
    __syncthreads();
    u16* dst = Vt + (long)sz * HD_ * T_;
    #pragma unroll
    for (int i = ty; i < 64; i += 4) dst[(long)i * T_ + t0 + tx] = Ts[tx][i];
}

// ---- R/S partials: RSp[chunk][idx][d1*64+d2] = sum_{j in chunk} mask*k[j,d1]*q[j,d2]
__global__ __launch_bounds__(256) void rs_part(const float* __restrict__ Uf,
                                               const float* __restrict__ Vf,
                                               const int* __restrict__ smask,
                                               const int* __restrict__ amask,
                                               float* __restrict__ RSp) {
    __shared__ float Ksh[64 * 64];
    __shared__ float Qsh[64 * 64];
    int idx = blockIdx.x;
    int mat = idx >> 5, z = idx & 31, b = z >> 4, h = z & 15;
    int chunk = blockIdx.y, j0 = chunk * 64;
    const float* base = mat ? Uf : Vf;
    const int* mk = mat ? smask : amask;
    int tid = threadIdx.x;
    float4* K4 = (float4*)Ksh;
    float4* Q4 = (float4*)Qsh;
    for (int ii = tid; ii < 1024; ii += 256) {
        int j = ii >> 4, d4 = ii & 15;
        long row = (long)(b * T_ + j0 + j) * 3072 + h * 64;
        int m = mk[b * T_ + j0 + j];
        float4 kv = ((const float4*)&base[row + 1024])[d4];
        if (m <= 0) kv = (float4){0.f, 0.f, 0.f, 0.f};
        K4[ii] = kv;
        Q4[ii] = ((const float4*)&base[row])[d4];
    }
    __syncthreads();
    int d1 = tid >> 2, c0 = (tid & 3) * 16;
    float4 a[4];
    #pragma unroll
    for (int k = 0; k < 4; k++) a[k] = (float4){0.f, 0.f, 0.f, 0.f};
    for (int j = 0; j < 64; j++) {
        float kv = Ksh[j * 64 + d1];
        const float4* q = (const float4*)&Qsh[j * 64 + c0];
        #pragma unroll
        for (int k = 0; k < 4; k++) {
            float4 qv = q[k];
            a[k].x += kv * qv.x; a[k].y += kv * qv.y;
            a[k].z += kv * qv.z; a[k].w += kv * qv.w;
        }
    }
    float4* out = (float4*)&RSp[((long)chunk * 64 + idx) * 4096 + d1 * 64 + c0];
    #pragma unroll
    for (int k = 0; k < 4; k++) out[k] = a[k];
}

// ---- RS[idx][e] = sum_{chunk<16} RSp[chunk][idx][e]  (float4-wide) -----------------
__global__ __launch_bounds__(256) void rs_reduce(const float* __restrict__ RSp,
                                                 float* __restrict__ RS) {
    int gid = blockIdx.x * 256 + threadIdx.x;    // 65536 float4s
    const float4* in = (const float4*)RSp;
    float4 s = (float4){0.f, 0.f, 0.f, 0.f};
    #pragma unroll
    for (int c = 0; c < 16; c++) {
        float4 v = in[(long)c * 65536 + gid];
        s.x += v.x; s.y += v.y; s.z += v.z; s.w += v.w;
    }
    ((float4*)RS)[gid] = s;
}

// ---------------- Q' = (Q @ R)/64, hi/lo split to [qhi|qlo] (128) -------------------
__global__ __launch_bounds__(256) void qprime(const float* __restrict__ Uf,
                                              const float* __restrict__ Vf,
                                              const float* __restrict__ RS,
                                              u16* __restrict__ Qs) {
    __shared__ float Rm[4096];
    __shared__ float Qsh[128][65];
    int t0 = blockIdx.x * 128;
    int sz = blockIdx.y, s = sz >> 5, z = sz & 31, b = z >> 4, h = z & 15;
    const float* Qf = s ? Vf : Uf;
    const float* mat = RS + (long)(s * 32 + z) * 4096;
    int tid = threadIdx.x;
    for (int ii = tid; ii < 1024; ii += 256)
        ((float4*)Rm)[ii] = ((const float4*)mat)[ii];
    for (int ii = tid; ii < 2048; ii += 256) {
        int j = ii >> 4, d4 = ii & 15;
        float4 v = ((const float4*)&Qf[(long)(b * T_ + t0 + j) * 3072 + h * 64])[d4];
        Qsh[j][d4 * 4] = v.x; Qsh[j][d4 * 4 + 1] = v.y;
        Qsh[j][d4 * 4 + 2] = v.z; Qsh[j][d4 * 4 + 3] = v.w;
    }
    __syncthreads();
    int r = tid >> 1, c0 = (tid & 1) * 32;
    float4 acc[8];
    #pragma unroll
    for (int k = 0; k < 8; k++) acc[k] = (float4){0.f, 0.f, 0.f, 0.f};
    for (int d1 = 0; d1 < 64; d1++) {
        float q = Qsh[r][d1];
        const float4* rm = (const float4*)&Rm[d1 * 64 + c0];
        #pragma unroll
        for (int k = 0; k < 8; k++) {
            float4 rv = rm[k];
            acc[k].x += q * rv.x; acc[k].y += q * rv.y;
            acc[k].z += q * rv.z; acc[k].w += q * rv.w;
        }
    }
    u16 hiA[32], loA[32];
    #pragma unroll
    for (int k = 0; k < 8; k++) {
        #pragma unroll
        for (int e = 0; e < 4; e++) {
            float x = ((const float*)&acc[k])[e] * (1.f / 64.f);
            int c = k * 4 + e;
            u16 hi = f2b(x);
            hiA[c] = hi;
            loA[c] = f2b(x - b2f(hi));
        }
    }
    u16* out = Qs + ((long)sz * T_ + (t0 + r)) * 128;
    #pragma unroll
    for (int i = 0; i < 4; i++) {
        *(u16x8*)&out[c0 + i * 8]      = *(const u16x8*)&hiA[i * 8];
        *(u16x8*)&out[64 + c0 + i * 8] = *(const u16x8*)&loA[i * 8];
    }
}

// ---------------- K split to [khi|klo] (128), masked rows zeroed --------------------
__global__ __launch_bounds__(256) void ksplit(const float* __restrict__ Uf,
                                              const float* __restrict__ Vf,
                                              const int* __restrict__ src_mask,
                                              const int* __restrict__ aux_mask,
                                              u16* __restrict__ Ks) {
    int t0 = blockIdx.x * 64;
    int sz = blockIdx.y, s = sz >> 5, z = sz & 31, b = z >> 4, h = z & 15;
    const float* Kf = s ? Vf : Uf;
    const int* mk = s ? aux_mask : src_mask;
    int tid = threadIdx.x;
    #pragma unroll
    for (int uu = 0; uu < 4; uu++) {
        int u = tid + uu * 256;             // 0..1023 = 64 rows x 16 16B-units
        int lr = u >> 4;
        int s16 = u & 15;                   // 0..15
        int seg = s16 >> 3;                 // 0:hi 1:lo
        int off = (s16 & 7) * 8;            // 0..56
        int r = t0 + lr;
        int m = mk[b * T_ + r];
        const float* srcp = &Kf[(long)(b * T_ + r) * 3072 + 1024 + h * 64 + off];
        float4 va = ((const float4*)srcp)[0];
        float4 vb = ((const float4*)srcp)[1];
        float xs[8] = {va.x, va.y, va.z, va.w, vb.x, vb.y, vb.z, vb.w};
        u16x8 wv;
        #pragma unroll
        for (int e = 0; e < 8; e++) {
            float x = (m > 0) ? xs[e] : 0.0f;
            u16 hi = f2b(x);
            wv[e] = (seg == 1) ? f2b(x - b2f(hi)) : hi;
        }
        *(u16x8*)&Ks[((long)sz * T_ + r) * 128 + seg * 64 + off] = wv;
    }
}

// ------- fused flash attention: logical K=192 via 128-phys hi/lo fragment reuse -----
// 512 threads (8 waves x 16 q-rows), KVBLK=64, K/V double-buffered, 64KB LDS.
__global__ __launch_bounds__(512, 4) void flash_comb(const u16* __restrict__ Qs,
                                                     const u16* __restrict__ Ks,
                                                     const u16* __restrict__ Vt,
                                                     u16* __restrict__ ctx2) {
    __shared__ u16 Ksh[2][64 * 128]; // [buf][row][unit c16 ^ (row&7)], 16KB each
    __shared__ u16 Vsh[2][64 * 64];  // [buf][d][unit c16 ^ (d&7)], 8KB each
    __shared__ u16 Psh[128 * 64];    // [q][col ^ ((q&7)<<3)], 16KB (32-bank span)
    const int tid = threadIdx.x, wave = tid >> 6, lane = tid & 63;
    const int z = blockIdx.x;
    const int m0 = blockIdx.y * 128;
    const int h = z & 15;
    const int g = lane >> 4, fr = lane & 15;
    const int wm = wave * 16;
    const u16* Qb = Qs + (long)z * T_ * 128;
    const u16* Kb = Ks + (long)z * T_ * 128;
    const u16* Vb = Vt + (long)z * HD_ * T_;

    // staging: 24 1KB slots (16 K + 8 V); wave w: slots {w, w+8, w+16}
    auto STAGE = [&](int k0, int buf) {
        #pragma unroll
        for (int t = 0; t < 3; t++) {
            int slot = wave + t * 8;
            if (slot < 16) {         // K: 64 rows x 16 units
                int o16 = slot * 64 + lane;
                int row = o16 >> 4, c16 = o16 & 15;
                gl2lds16(Kb + (long)(k0 + row) * 128 + ((c16 ^ (row & 7)) * 8),
                         &Ksh[buf][slot * 512]);
            } else {                 // V: 64 d-rows x 8 units
                int o16 = (slot - 16) * 64 + lane;
                int d = o16 >> 3, c16 = o16 & 7;
                gl2lds16(Vb + (long)d * T_ + k0 + ((c16 ^ (d & 7)) * 8),
                         &Vsh[buf][(slot - 16) * 512]);
            }
        }
    };

    // Q' phys fragments (4): [qhi chunk0, qhi chunk1, qlo chunk0, qlo chunk1]
    bf16x8 qA[4];
    #pragma unroll
    for (int p = 0; p < 4; p++)
        qA[p] = *(const bf16x8*)&Qb[(long)(m0 + wm + fr) * 128 + p * 32 + g * 8];

    f32x4 oacc[4], mrun, lrun;
    mrun = (f32x4){-1e30f, -1e30f, -1e30f, -1e30f};
    lrun = (f32x4){0.f, 0.f, 0.f, 0.f};
    #pragma unroll
    for (int dj = 0; dj < 4; dj++) oacc[dj] = (f32x4){0.f, 0.f, 0.f, 0.f};

    STAGE(0, 0);
    __syncthreads();

    #pragma unroll 1
    for (int kt = 0; kt < 16; kt++) {
        const int buf = kt & 1;
        if (kt < 15) STAGE((kt + 1) * 64, buf ^ 1);   // prefetch overlaps compute

        // S = Q' K^T (16 q-rows x 64 k-cols), logical K=192 via fragment reuse:
        //   S = qhi.khi + qlo.khi + qhi.klo  (chunked over 2 MFMA k-slices each)
        f32x4 sacc[4];
        #pragma unroll
        for (int ki = 0; ki < 4; ki++) sacc[ki] = (f32x4){0.f, 0.f, 0.f, 0.f};
        __builtin_amdgcn_s_setprio(1);
        {
            bf16x8 kb[2][4];
            // khi chunks (units [0,8))
            #pragma unroll
            for (int pk = 0; pk < 2; pk++)
                #pragma unroll
                for (int ki = 0; ki < 4; ki++) {
                    int row = ki * 16 + fr;
                    kb[pk][ki] = *(const bf16x8*)&Ksh[buf][row * 128 + (((pk * 4 + g) ^ (row & 7)) * 8)];
                }
            #pragma unroll
            for (int ki = 0; ki < 4; ki++) {
                sacc[ki] = __builtin_amdgcn_mfma_f32_16x16x32_bf16(qA[0], kb[0][ki], sacc[ki], 0, 0, 0);
                sacc[ki] = __builtin_amdgcn_mfma_f32_16x16x32_bf16(qA[1], kb[1][ki], sacc[ki], 0, 0, 0);
                sacc[ki] = __builtin_amdgcn_mfma_f32_16x16x32_bf16(qA[2], kb[0][ki], sacc[ki], 0, 0, 0);
                sacc[ki] = __builtin_amdgcn_mfma_f32_16x16x32_bf16(qA[3], kb[1][ki], sacc[ki], 0, 0, 0);
            }
            // klo chunks (units [8,16))
            #pragma unroll
            for (int pk = 0; pk < 2; pk++)
                #pragma unroll
                for (int ki = 0; ki < 4; ki++) {
                    int row = ki * 16 + fr;
                    kb[pk][ki] = *(const bf16x8*)&Ksh[buf][row * 128 + ((((pk + 2) * 4 + g) ^ (row & 7)) * 8)];
                }
            #pragma unroll
            for (int ki = 0; ki < 4; ki++) {
                sacc[ki] = __builtin_amdgcn_mfma_f32_16x16x32_bf16(qA[0], kb[0][ki], sacc[ki], 0, 0, 0);
                sacc[ki] = __builtin_amdgcn_mfma_f32_16x16x32_bf16(qA[1], kb[1][ki], sacc[ki], 0, 0, 0);
            }
        }
        __builtin_amdgcn_s_setprio(0);

        // online softmax in C-layout: row = wm + g*4+e, col = ki*16+fr; tree max
        f32x4 tm;
        #pragma unroll
        for (int e = 0; e < 4; e++)
            tm[e] = fmaxf(fmaxf(sacc[0][e], sacc[1][e]), fmaxf(sacc[2][e], sacc[3][e]));
        #pragma unroll
        for (int off = 1; off < 16; off <<= 1)
            #pragma unroll
            for (int e = 0; e < 4; e++) tm[e] = fmaxf(tm[e], shx(tm[e], off));

        // defer-max (T13): only rescale when tile max grew past mrun + 8
        int within = (tm[0] <= mrun[0] + 8.f) && (tm[1] <= mrun[1] + 8.f) &&
                     (tm[2] <= mrun[2] + 8.f) && (tm[3] <= mrun[3] + 8.f);
        if (!__all(within)) {
            f32x4 alpha;
            #pragma unroll
            for (int e = 0; e < 4; e++) {
                float mnew = fmaxf(mrun[e], tm[e]);
                alpha[e] = __expf(mrun[e] - mnew);
                mrun[e] = mnew;
            }
            #pragma unroll
            for (int dj = 0; dj < 4; dj++)
                #pragma unroll
                for (int e = 0; e < 4; e++) oacc[dj][e] *= alpha[e];
            #pragma unroll
            for (int e = 0; e < 4; e++) lrun[e] *= alpha[e];
        }

        f32x4 psum = (f32x4){0.f, 0.f, 0.f, 0.f};
        #pragma unroll
        for (int ki = 0; ki < 4; ki++) {
            #pragma unroll
            for (int e = 0; e < 4; e++) {
                float p = __expf(sacc[ki][e] - mrun[e]);
                psum[e] += p;
                int row = wm + g * 4 + e;
                Psh[row * 64 + ((ki * 16 + fr) ^ ((row & 7) << 3))] = f2b(p);
            }
        }
        #pragma unroll
        for (int off = 1; off < 16; off <<= 1)
            #pragma unroll
            for (int e = 0; e < 4; e++) psum[e] += shx(psum[e], off);
        #pragma unroll
        for (int e = 0; e < 4; e++) lrun[e] += psum[e];

        // PV: O += P @ V (P via LDS round-trip C-layout -> A-layout, wave-private)
        bf16x8 pa[2];
        #pragma unroll
        for (int ks = 0; ks < 2; ks++) {
            int row = wm + fr;
            pa[ks] = *(const bf16x8*)&Psh[row * 64 + (((ks * 4 + g) ^ (row & 7)) * 8)];
        }
        __builtin_amdgcn_s_setprio(1);
        #pragma unroll
        for (int dj = 0; dj < 4; dj++) {
            int d = dj * 16 + fr;
            bf16x8 vb0 = *(const bf16x8*)&Vsh[buf][d * 64 + (((0 * 4 + g) ^ (d & 7)) * 8)];
            bf16x8 vb1 = *(const bf16x8*)&Vsh[buf][d * 64 + (((1 * 4 + g) ^ (d & 7)) * 8)];
            oacc[dj] = __builtin_amdgcn_mfma_f32_16x16x32_bf16(pa[0], vb0, oacc[dj], 0, 0, 0);
            oacc[dj] = __builtin_amdgcn_mfma_f32_16x16x32_bf16(pa[1], vb1, oacc[dj], 0, 0, 0);
        }
        __builtin_amdgcn_s_setprio(0);
        __syncthreads();   // drains prefetch vmcnt (overlapped) + guards buf reuse
    }

    // epilogue: O /= l; ctx2 flat [4096][1024], row = (z>>4)*T + qr
    f32x4 inv;
    #pragma unroll
    for (int e = 0; e < 4; e++) inv[e] = 1.f / lrun[e];
    #pragma unroll
    for (int dj = 0; dj < 4; dj++)
        #pragma unroll
        for (int e = 0; e < 4; e++) {
            int qr = m0 + wm + g * 4 + e;
            int dc = dj * 16 + fr;
            ctx2[((long)((z >> 4) * T_ + qr)) * D_ + h * 64 + dc] = f2b(oacc[dj][e] * inv[e]);
        }
}

// ------- fused residual-add + LayerNorm, dual-stream batched (4096 rows) ------------
template <bool XF32, bool OUTF32>
__global__ __launch_bounds__(256) void ln_fused2(const void* __restrict__ x0,
                                                 const void* __restrict__ x1,
                                                 const u16* __restrict__ y,
                                                 const float* __restrict__ g,
                                                 const float* __restrict__ be,
                                                 void* __restrict__ out) {
    __shared__ float red[8];
    int row = blockIdx.x;
    const void* xp = (row < 2048) ? x0 : x1;
    long xbase = (long)((row < 2048) ? row : row - 2048) * 1024;
    long base = (long)row * 1024;
    int tid = threadIdx.x, wave = tid >> 6, lane = tid & 63;
    float v[4];
    #pragma unroll
    for (int i = 0; i < 4; i++) {
        int c = tid + i * 256;
        float xv = XF32 ? ((const float*)xp)[xbase + c] : b2f(((const u16*)xp)[xbase + c]);
        v[i] = xv + b2f(y[base + c]);
    }
    float s = v[0] + v[1] + v[2] + v[3];
    float q = v[0] * v[0] + v[1] * v[1] + v[2] * v[2] + v[3] * v[3];
    s = wred_sum(s);
    q = wred_sum(q);
    if (lane == 0) { red[wave] = s; red[4 + wave] = q; }
    __syncthreads();
    s = red[0] + red[1] + red[2] + red[3];
    q = red[4] + red[5] + red[6] + red[7];
    float mean = s * (1.f / 1024.f);
    float var = q * (1.f / 1024.f) - mean * mean;
    float inv = rsqrtf(var + 1e-5f);
    #pragma unroll
    for (int i = 0; i < 4; i++) {
        int c = tid + i * 256;
        float o = (v[i] - mean) * inv * g[c] + be[c];
        if (OUTF32) ((float*)out)[base + c] = o;
        else ((u16*)out)[base + c] = f2b(o);
    }
}

extern "C" void kernel_launch(void* const* d_in, const int* in_sizes, int n_in,
                              void* d_out, int out_size, void* d_ws, size_t ws_size,
                              hipStream_t stream) {
    const float* src = (const float*)d_in[0];
    const float* aux = (const float*)d_in[1];
    const float* Wu = (const float*)d_in[2];
    const float* bu = (const float*)d_in[3];
    const float* Wv = (const float*)d_in[4];
    const float* bv = (const float*)d_in[5];
    const float* Wo = (const float*)d_in[6];
    const float* bo = (const float*)d_in[7];
    const float* W1 = (const float*)d_in[8];
    const float* b1 = (const float*)d_in[9];
    const float* W2 = (const float*)d_in[10];
    const float* b2 = (const float*)d_in[11];
    const float* g1 = (const float*)d_in[12];
    const float* be1 = (const float*)d_in[13];
    const float* g2 = (const float*)d_in[14];
    const float* be2 = (const float*)d_in[15];
    const int* src_mask = (const int*)d_in[16];
    const int* aux_mask = (const int*)d_in[17];

    // -------- workspace (time-phased; ~148 MiB peak < 159 proven) --------------------
    char* w = (char*)d_ws;
    auto alloc = [&](size_t bytes) { char* p = w; w += (bytes + 255) & ~(size_t)255; return p; };
    // permanent (~59 MiB)
    u16* WoT = (u16*)alloc(1024L * 1024 * 2);
    u16* W1T = (u16*)alloc(4096L * 1024 * 2);
    u16* W2T = (u16*)alloc(1024L * 4096 * 2);
    u16* Vt  = (u16*)alloc(64L * 64 * 1024 * 2);
    float* RS = (float*)alloc(64L * 4096 * 4);
    u16* Qs = (u16*)alloc(64L * 1024 * 128 * 2);    // [qhi|qlo] 128-phys
    u16* Ks = (u16*)alloc(64L * 1024 * 128 * 2);    // [khi|klo] 128-phys
    // scratch union: 89 MiB, two time-phases
    char* scratch = (char*)alloc(89L * 1024 * 1024);
    // phase A: WS2 (both split weights), As2 (both split inputs), UVf (both outputs)
    u16* WS2 = (u16*)(scratch);                        // 25165824 (2 x 3072x2048 bf16)
    u16* As2 = (u16*)(scratch + 25165824L);            // 16777216 (2 x 2048x2048 bf16)
    float* UVf = (float*)(scratch + 41943040L);        // 50331648 (2 x 2048x3072 f32)
    float* Uf = UVf;
    float* Vf = UVf + 6291456L;
    float* RSp = (float*)(scratch);                    // 16777216 (aliases dead WS2)
    // phase B (overlays phase-A scratch, all of which is dead by then)
    u16* ctx2   = (u16*)(scratch);                     // 8388608  [4096][1024] bf16
    u16* attn_s = (u16*)(scratch + 8388608L);          // 8388608
    u16* o1s    = (u16*)(scratch + 16777216L);         // 8388608
    u16* hbuf   = (u16*)(scratch + 25165824L);         // 33554432 [2][2048][4096]
    u16* fbuf   = (u16*)(scratch + 58720256L);         // 8388608  (ends 67108864)

    // -------- phase A: weight prep + hi/lo QKV projections + R/S + Q'/K splits ------
    transpose_cvt<<<dim3(16, 16), 256, 0, stream>>>(Wo, WoT, 1024, 1024);
    transpose_cvt<<<dim3(64, 16), 256, 0, stream>>>(W1, W1T, 1024, 4096);
    transpose_cvt<<<dim3(16, 64), 256, 0, stream>>>(W2, W2T, 4096, 1024);

    wsplit2<<<dim3(48, 16), 256, 0, stream>>>(Wu, WS2, 1024, 3072);
    wsplit2<<<dim3(48, 16), 256, 0, stream>>>(Wv, WS2 + 6291456L, 1024, 3072);
    split2<<<dim3(2048, 2), 256, 0, stream>>>(src, aux, As2);
    gemm_hl<<<dim3(16, 24, 2), 256, 0, stream>>>(
        As2, WS2, UVf, bu, bv, 4194304L, 6291456L, 6291456L);
    // WS2/As2 dead from here; RSp aliases
    repack_vt<<<dim3(16, 64), 256, 0, stream>>>(Uf, Vf, Vt);
    rs_part<<<dim3(64, 16), 256, 0, stream>>>(Uf, Vf, src_mask, aux_mask, RSp);
    rs_reduce<<<256, 256, 0, stream>>>(RSp, RS);
    qprime<<<dim3(8, 64), 256, 0, stream>>>(Uf, Vf, RS, Qs);
    ksplit<<<dim3(16, 64), 256, 0, stream>>>(Uf, Vf, src_mask, aux_mask, Ks);
    // ---- phase A scratch dead; phase B overlays -------------------------------------

    // fused comb + softmax + PV for all 64 (s,b,h) slices in one launch
    flash_comb<<<dim3(64, 8), 512, 0, stream>>>(Qs, Ks, Vt, ctx2);

    // -------- phase B: dual-stream batched (z = stream) ------------------------------
    gemm128<EPI_BF16_BIAS, 64><<<dim3(16, 16, 2), 256, 0, stream>>>(
        ctx2, WoT, attn_s, bo, 2048, 1024, 1024, 1024, 1024, 1024,
        2048L * 1024, 0, 2048L * 1024);
    ln_fused2<true, false><<<4096, 256, 0, stream>>>(src, aux, attn_s, g1, be1, o1s);
    gemm128<EPI_BF16_BIAS_RELU, 128><<<dim3(16, 32, 2), 256, 0, stream>>>(
        o1s, W1T, hbuf, b1, 2048, 4096, 1024, 1024, 1024, 4096,
        2048L * 1024, 0, 2048L * 4096);
    gemm128<EPI_BF16_BIAS, 64><<<dim3(16, 16, 2), 256, 0, stream>>>(
        hbuf, W2T, fbuf, b2, 2048, 1024, 4096, 4096, 4096, 1024,
        2048L * 4096, 0, 2048L * 1024);
    ln_fused2<false, true><<<4096, 256, 0, stream>>>(o1s, o1s + 2048L * 1024, fbuf,
                                                     g2, be2, (float*)d_out);
}

// Round 11
// 488.154 us; speedup vs baseline: 1.2474x; 1.0419x over previous
//
#include <hip/hip_runtime.h>
#include <stdint.h>

typedef unsigned short u16;
typedef __attribute__((ext_vector_type(4))) float f32x4;
typedef __attribute__((ext_vector_type(8))) __bf16 bf16x8;
typedef __attribute__((ext_vector_type(8))) unsigned short u16x8;

#define T_ 1024
#define D_ 1024
#define HD_ 64

__device__ __forceinline__ float b2f(u16 u) {
    union { unsigned int i; float f; } x; x.i = ((unsigned int)u) << 16; return x.f;
}
__device__ __forceinline__ u16 f2b(float f) {
    union { float f; unsigned int i; } x; x.f = f;
    unsigned int i = x.i;
    unsigned int r = (i >> 16) & 1;
    i += 0x7fffu + r;
    return (u16)(i >> 16);
}

// async global->LDS, 16B per lane; LDS dest is wave-uniform base + lane*16
__device__ __forceinline__ void gl2lds16(const void* g, void* l) {
    auto gp = (const __attribute__((address_space(1))) unsigned int*)(unsigned long long)(g);
    auto lp = (__attribute__((address_space(3))) unsigned int*)(unsigned int)(unsigned long long)(l);
    __builtin_amdgcn_global_load_lds(gp, lp, 16, 0, 0);
}

__device__ __forceinline__ float wred_sum(float v) {
    #pragma unroll
    for (int o = 32; o > 0; o >>= 1) v += __shfl_down(v, o, 64);
    return v;
}
__device__ __forceinline__ float shx(float v, int m) { return __shfl_xor(v, m, 64); }

// ---------------- f32 transpose + bf16 convert: out[c*R + r] = bf16(in[r*C + c]) ----
__global__ __launch_bounds__(256) void transpose_cvt(const float* __restrict__ in,
                                                     u16* __restrict__ out, int R, int C) {
    __shared__ float Ts[64][65];
    int c0 = blockIdx.x * 64, r0 = blockIdx.y * 64;
    int tid = threadIdx.x, tx = tid & 63, ty = tid >> 6;
    #pragma unroll
    for (int i = ty; i < 64; i += 4) Ts[i][tx] = in[(long)(r0 + i) * C + c0 + tx];
    __syncthreads();
    #pragma unroll
    for (int i = ty; i < 64; i += 4)
        out[(long)(c0 + i) * R + r0 + tx] = f2b(Ts[tx][i]);
}

// ---- f32 transpose + hi/lo split: W[R,C] -> out[C, 2R] = [hi | lo] -----------------
__global__ __launch_bounds__(256) void wsplit2(const float* __restrict__ in,
                                               u16* __restrict__ out, int R, int C) {
    __shared__ float Ts[64][65];
    int c0 = blockIdx.x * 64, r0 = blockIdx.y * 64;
    int tid = threadIdx.x, tx = tid & 63, ty = tid >> 6;
    #pragma unroll
    for (int i = ty; i < 64; i += 4) Ts[i][tx] = in[(long)(r0 + i) * C + c0 + tx];
    __syncthreads();
    #pragma unroll
    for (int i = ty; i < 64; i += 4) {
        float v = Ts[tx][i];
        u16 hi = f2b(v);
        u16 lo = f2b(v - b2f(hi));
        long base = (long)(c0 + i) * (2 * R) + r0 + tx;
        out[base] = hi;
        out[base + R] = lo;
    }
}

// ---- f32 rowwise hi/lo split: X[M,1024] -> out[M, 2048] = [hi | lo], z-batched -----
__global__ __launch_bounds__(256) void split2(const float* __restrict__ x0,
                                              const float* __restrict__ x1,
                                              u16* __restrict__ out) {
    long row = blockIdx.x;
    int z = blockIdx.y;
    const float* in = z ? x1 : x0;
    u16* o = out + (long)z * 2048 * 2048;
    int tid = threadIdx.x;
    #pragma unroll
    for (int k = 0; k < 4; k++) {
        int c = tid + k * 256;
        float v = in[row * 1024 + c];
        u16 hi = f2b(v);
        u16 lo = f2b(v - b2f(hi));
        o[row * 2048 + c] = hi;
        o[row * 2048 + 1024 + c] = lo;
    }
}

enum { EPI_F32_BIAS = 0, EPI_BF16_BIAS = 1, EPI_BF16_BIAS_RELU = 2 };

// ------- BK=64 BT GEMM (gemm_hl staging structure, plain bf16), z-batched -----------
// 32 MFMA/barrier at BN=128, 16 at BN=64. Linear LDS dest + inverse-swizzled source
// col; read-side unit XOR l^(row&7) (measured 0 conflicts in gemm_hl).
template <int EPI, int BN>
__global__ __launch_bounds__(256) void gemm64(
    const u16* __restrict__ A, const u16* __restrict__ B, void* __restrict__ C,
    const float* __restrict__ bias,
    int M, int N, int K, int lda, int ldb, int ldc,
    long sAz, long sBz, long sCz) {
    __shared__ u16 As[2][128 * 64];
    __shared__ u16 Bs[2][BN * 64];
    const int tid = threadIdx.x, wave = tid >> 6, lane = tid & 63;
    const int m0 = blockIdx.x * 128, n0 = blockIdx.y * BN;
    const int z = blockIdx.z;
    const u16* Ab = A + (long)z * sAz;
    const u16* Bb = B + (long)z * sBz;
    const int fr = lane & 15, g = lane >> 4;
    constexpr int IT = (BN == 128) ? 4 : 2;
    const int wm = (BN == 128) ? (wave >> 1) * 64 : wave * 32;
    const int wn = (BN == 128) ? (wave & 1) * 64 : 0;
    f32x4 acc[IT][4];
    #pragma unroll
    for (int i = 0; i < IT; i++)
        #pragma unroll
        for (int j = 0; j < 4; j++) acc[i][j] = (f32x4){0.f, 0.f, 0.f, 0.f};

    constexpr int ASLOTS = 16;            // 128 rows x 8 units / 64 lanes
    constexpr int BSLOTS = BN * 8 / 64;   // 16 or 8
    constexpr int PER = (ASLOTS + BSLOTS) / 4;
    auto STAGE = [&](int k0, int buf) {
        #pragma unroll
        for (int t = 0; t < PER; t++) {
            int slot = wave * PER + t;
            if (slot < ASLOTS) {
                int o16 = slot * 64 + lane;
                int row = o16 >> 3, p = o16 & 7;
                int l = p ^ (row & 7);
                gl2lds16(Ab + (long)(m0 + row) * lda + k0 + l * 8, &As[buf][slot * 512]);
            } else {
                int s2 = slot - ASLOTS;
                int o16 = s2 * 64 + lane;
                int row = o16 >> 3, p = o16 & 7;
                int l = p ^ (row & 7);
                gl2lds16(Bb + (long)(n0 + row) * ldb + k0 + l * 8, &Bs[buf][s2 * 512]);
            }
        }
    };

    STAGE(0, 0);
    __syncthreads();

    for (int k0 = 0; k0 < K; k0 += 64) {
        const int buf = (k0 >> 6) & 1;
        if (k0 + 64 < K) STAGE(k0 + 64, buf ^ 1);   // prefetch overlaps compute
        bf16x8 af[IT][2], bv[4][2];
        #pragma unroll
        for (int i = 0; i < IT; i++) {
            int r = wm + i * 16 + fr;
            #pragma unroll
            for (int s = 0; s < 2; s++)
                af[i][s] = *(const bf16x8*)&As[buf][r * 64 + (((s * 4 + g) ^ (r & 7)) * 8)];
        }
        #pragma unroll
        for (int j = 0; j < 4; j++) {
            int r = wn + j * 16 + fr;
            #pragma unroll
            for (int s = 0; s < 2; s++)
                bv[j][s] = *(const bf16x8*)&Bs[buf][r * 64 + (((s * 4 + g) ^ (r & 7)) * 8)];
        }
        #pragma unroll
        for (int i = 0; i < IT; i++)
            #pragma unroll
            for (int j = 0; j < 4; j++) {
                acc[i][j] = __builtin_amdgcn_mfma_f32_16x16x32_bf16(af[i][0], bv[j][0], acc[i][j], 0, 0, 0);
                acc[i][j] = __builtin_amdgcn_mfma_f32_16x16x32_bf16(af[i][1], bv[j][1], acc[i][j], 0, 0, 0);
            }
        __syncthreads();   // drains prefetch vmcnt (overlapped) + guards buf reuse
    }
    const int er = (lane >> 4) * 4, ec = lane & 15;
    #pragma unroll
    for (int i = 0; i < IT; i++)
        #pragma unroll
        for (int j = 0; j < 4; j++)
            #pragma unroll
            for (int r = 0; r < 4; r++) {
                const int gm = m0 + wm + i * 16 + er + r;
                const int gn = n0 + wn + j * 16 + ec;
                const float v = acc[i][j][r];
                if constexpr (EPI == EPI_F32_BIAS) {
                    ((float*)C)[(long)z * sCz + (long)gm * ldc + gn] = v + bias[gn];
                } else if constexpr (EPI == EPI_BF16_BIAS) {
                    ((u16*)C)[(long)z * sCz + (long)gm * ldc + gn] = f2b(v + bias[gn]);
                } else {
                    ((u16*)C)[(long)z * sCz + (long)gm * ldc + gn] = f2b(fmaxf(v + bias[gn], 0.0f));
                }
            }
}

// ------- QKV GEMM with hi/lo fragment reuse: C = xhi.whi + xlo.whi + xhi.wlo --------
__global__ __launch_bounds__(256) void gemm_hl(
    const u16* __restrict__ A, const u16* __restrict__ B, float* __restrict__ C,
    const float* __restrict__ bias0, const float* __restrict__ bias1,
    long sAz, long sBz, long sCz) {
    __shared__ u16 As[2][128 * 64];   // [buf][row][8 units; phys = l ^ (row&7)]
    __shared__ u16 Bs[2][128 * 64];
    const int tid = threadIdx.x, wave = tid >> 6, lane = tid & 63;
    const int m0 = blockIdx.x * 128, n0 = blockIdx.y * 128;
    const int z = blockIdx.z;
    const u16* Ab = A + (long)z * sAz;
    const u16* Bb = B + (long)z * sBz;
    const float* bp = z ? bias1 : bias0;
    const int fr = lane & 15, g = lane >> 4;
    const int wm = (wave >> 1) * 64, wn = (wave & 1) * 64;
    f32x4 acc[4][4];
    #pragma unroll
    for (int i = 0; i < 4; i++)
        #pragma unroll
        for (int j = 0; j < 4; j++) acc[i][j] = (f32x4){0.f, 0.f, 0.f, 0.f};

    auto STAGE = [&](int k0, int buf) {
        #pragma unroll
        for (int t = 0; t < 8; t++) {
            int slot = wave * 8 + t;
            int o16 = (slot & 15) * 64 + lane;
            int row = o16 >> 3, p = o16 & 7;
            int l = p ^ (row & 7);
            int srccol = (l < 4) ? (k0 + l * 8) : (1024 + k0 + (l - 4) * 8);
            if (slot < 16)
                gl2lds16(Ab + (long)(m0 + row) * 2048 + srccol, &As[buf][(slot & 15) * 512]);
            else
                gl2lds16(Bb + (long)(n0 + row) * 2048 + srccol, &Bs[buf][(slot & 15) * 512]);
        }
    };

    STAGE(0, 0);
    __syncthreads();

    for (int k0 = 0; k0 < 1024; k0 += 32) {
        const int buf = (k0 >> 5) & 1;
        if (k0 + 32 < 1024) STAGE(k0 + 32, buf ^ 1);   // prefetch overlaps compute
        bf16x8 ah[4], al[4], bh[4], bl[4];
        #pragma unroll
        for (int i = 0; i < 4; i++) {
            int r = wm + i * 16 + fr;
            ah[i] = *(const bf16x8*)&As[buf][r * 64 + ((g ^ (r & 7)) * 8)];
            al[i] = *(const bf16x8*)&As[buf][r * 64 + (((4 + g) ^ (r & 7)) * 8)];
        }
        #pragma unroll
        for (int j = 0; j < 4; j++) {
            int r = wn + j * 16 + fr;
            bh[j] = *(const bf16x8*)&Bs[buf][r * 64 + ((g ^ (r & 7)) * 8)];
            bl[j] = *(const bf16x8*)&Bs[buf][r * 64 + (((4 + g) ^ (r & 7)) * 8)];
        }
        #pragma unroll
        for (int i = 0; i < 4; i++)
            #pragma unroll
            for (int j = 0; j < 4; j++) {
                acc[i][j] = __builtin_amdgcn_mfma_f32_16x16x32_bf16(ah[i], bh[j], acc[i][j], 0, 0, 0);
                acc[i][j] = __builtin_amdgcn_mfma_f32_16x16x32_bf16(al[i], bh[j], acc[i][j], 0, 0, 0);
                acc[i][j] = __builtin_amdgcn_mfma_f32_16x16x32_bf16(ah[i], bl[j], acc[i][j], 0, 0, 0);
            }
        __syncthreads();   // drains prefetch vmcnt (overlapped) + guards buf reuse
    }
    const int er = (lane >> 4) * 4, ec = lane & 15;
    #pragma unroll
    for (int i = 0; i < 4; i++)
        #pragma unroll
        for (int j = 0; j < 4; j++)
            #pragma unroll
            for (int r = 0; r < 4; r++) {
                const int gm = m0 + wm + i * 16 + er + r;
                const int gn = n0 + wn + j * 16 + ec;
                C[(long)z * sCz + (long)gm * 3072 + gn] = acc[i][j][r] + bp[gn];
            }
}

// ---------------- repack V^T: Vt[s,z,d,t] = U/Vf[b*T+t, 2048+h*64+d] ----------------
__global__ __launch_bounds__(256) void repack_vt(const float* __restrict__ Uf,
                                                 const float* __restrict__ Vf,
                                                 u16* __restrict__ Vt) {
    __shared__ u16 Ts[64][65];
    int tid = threadIdx.x, tx = tid & 63, ty = tid >> 6;
    int t0 = blockIdx.x * 64;
    int sz = blockIdx.y, s = sz >> 5, z = sz & 31, b = z >> 4, h = z & 15;
    const float* srcp = s ? Vf : Uf;
    #pragma unroll
    for (int i = ty; i < 64; i += 4)
        Ts[i][tx] = f2b(srcp[(long)(b * T_ + t0 + i) * 3072 + 2048 + h * 64 + tx]);
    __syncthreads();
    u16* dst = Vt + (long)sz * HD_ * T_;
    #pragma unroll
    for (int i = ty; i < 64; i += 4) dst[(long)i * T_ + t0 + tx] = Ts[tx][i];
}

// ---- R/S partials: RSp[chunk][idx][d1*64+d2] = sum_{j in chunk} mask*k[j,d1]*q[j,d2]
__global__ __launch_bounds__(256) void rs_part(const float* __restrict__ Uf,
                                               const float* __restrict__ Vf,
                                               const int* __restrict__ smask,
                                               const int* __restrict__ amask,
                                               float* __restrict__ RSp) {
    __shared__ float Ksh[64 * 64];
    __shared__ float Qsh[64 * 64];
    int idx = blockIdx.x;
    int mat = idx >> 5, z = idx & 31, b = z >> 4, h = z & 15;
    int chunk = blockIdx.y, j0 = chunk * 64;
    const float* base = mat ? Uf : Vf;
    const int* mk = mat ? smask : amask;
    int tid = threadIdx.x;
    float4* K4 = (float4*)Ksh;
    float4* Q4 = (float4*)Qsh;
    for (int ii = tid; ii < 1024; ii += 256) {
        int j = ii >> 4, d4 = ii & 15;
        long row = (long)(b * T_ + j0 + j) * 3072 + h * 64;
        int m = mk[b * T_ + j0 + j];
        float4 kv = ((const float4*)&base[row + 1024])[d4];
        if (m <= 0) kv = (float4){0.f, 0.f, 0.f, 0.f};
        K4[ii] = kv;
        Q4[ii] = ((const float4*)&base[row])[d4];
    }
    __syncthreads();
    int d1 = tid >> 2, c0 = (tid & 3) * 16;
    float4 a[4];
    #pragma unroll
    for (int k = 0; k < 4; k++) a[k] = (float4){0.f, 0.f, 0.f, 0.f};
    for (int j = 0; j < 64; j++) {
        float kv = Ksh[j * 64 + d1];
        const float4* q = (const float4*)&Qsh[j * 64 + c0];
        #pragma unroll
        for (int k = 0; k < 4; k++) {
            float4 qv = q[k];
            a[k].x += kv * qv.x; a[k].y += kv * qv.y;
            a[k].z += kv * qv.z; a[k].w += kv * qv.w;
        }
    }
    float4* out = (float4*)&RSp[((long)chunk * 64 + idx) * 4096 + d1 * 64 + c0];
    #pragma unroll
    for (int k = 0; k < 4; k++) out[k] = a[k];
}

// ---- RS[idx][e] = sum_{chunk<16} RSp[chunk][idx][e]  (float4-wide) -----------------
__global__ __launch_bounds__(256) void rs_reduce(const float* __restrict__ RSp,
                                                 float* __restrict__ RS) {
    int gid = blockIdx.x * 256 + threadIdx.x;    // 65536 float4s
    const float4* in = (const float4*)RSp;
    float4 s = (float4){0.f, 0.f, 0.f, 0.f};
    #pragma unroll
    for (int c = 0; c < 16; c++) {
        float4 v = in[(long)c * 65536 + gid];
        s.x += v.x; s.y += v.y; s.z += v.z; s.w += v.w;
    }
    ((float4*)RS)[gid] = s;
}

// ---------------- Q' = (Q @ R)/64, hi/lo split to [qhi|qlo] (128) -------------------
__global__ __launch_bounds__(256) void qprime(const float* __restrict__ Uf,
                                              const float* __restrict__ Vf,
                                              const float* __restrict__ RS,
                                              u16* __restrict__ Qs) {
    __shared__ float Rm[4096];
    __shared__ float Qsh[128][65];
    int t0 = blockIdx.x * 128;
    int sz = blockIdx.y, s = sz >> 5, z = sz & 31, b = z >> 4, h = z & 15;
    const float* Qf = s ? Vf : Uf;
    const float* mat = RS + (long)(s * 32 + z) * 4096;
    int tid = threadIdx.x;
    for (int ii = tid; ii < 1024; ii += 256)
        ((float4*)Rm)[ii] = ((const float4*)mat)[ii];
    for (int ii = tid; ii < 2048; ii += 256) {
        int j = ii >> 4, d4 = ii & 15;
        float4 v = ((const float4*)&Qf[(long)(b * T_ + t0 + j) * 3072 + h * 64])[d4];
        Qsh[j][d4 * 4] = v.x; Qsh[j][d4 * 4 + 1] = v.y;
        Qsh[j][d4 * 4 + 2] = v.z; Qsh[j][d4 * 4 + 3] = v.w;
    }
    __syncthreads();
    int r = tid >> 1, c0 = (tid & 1) * 32;
    float4 acc[8];
    #pragma unroll
    for (int k = 0; k < 8; k++) acc[k] = (float4){0.f, 0.f, 0.f, 0.f};
    for (int d1 = 0; d1 < 64; d1++) {
        float q = Qsh[r][d1];
        const float4* rm = (const float4*)&Rm[d1 * 64 + c0];
        #pragma unroll
        for (int k = 0; k < 8; k++) {
            float4 rv = rm[k];
            acc[k].x += q * rv.x; acc[k].y += q * rv.y;
            acc[k].z += q * rv.z; acc[k].w += q * rv.w;
        }
    }
    u16 hiA[32], loA[32];
    #pragma unroll
    for (int k = 0; k < 8; k++) {
        #pragma unroll
        for (int e = 0; e < 4; e++) {
            float x = ((const float*)&acc[k])[e] * (1.f / 64.f);
            int c = k * 4 + e;
            u16 hi = f2b(x);
            hiA[c] = hi;
            loA[c] = f2b(x - b2f(hi));
        }
    }
    u16* out = Qs + ((long)sz * T_ + (t0 + r)) * 128;
    #pragma unroll
    for (int i = 0; i < 4; i++) {
        *(u16x8*)&out[c0 + i * 8]      = *(const u16x8*)&hiA[i * 8];
        *(u16x8*)&out[64 + c0 + i * 8] = *(const u16x8*)&loA[i * 8];
    }
}

// ---------------- K split to [khi|klo] (128), masked rows zeroed --------------------
__global__ __launch_bounds__(256) void ksplit(const float* __restrict__ Uf,
                                              const float* __restrict__ Vf,
                                              const int* __restrict__ src_mask,
                                              const int* __restrict__ aux_mask,
                                              u16* __restrict__ Ks) {
    int t0 = blockIdx.x * 64;
    int sz = blockIdx.y, s = sz >> 5, z = sz & 31, b = z >> 4, h = z & 15;
    const float* Kf = s ? Vf : Uf;
    const int* mk = s ? aux_mask : src_mask;
    int tid = threadIdx.x;
    #pragma unroll
    for (int uu = 0; uu < 4; uu++) {
        int u = tid + uu * 256;             // 0..1023 = 64 rows x 16 16B-units
        int lr = u >> 4;
        int s16 = u & 15;                   // 0..15
        int seg = s16 >> 3;                 // 0:hi 1:lo
        int off = (s16 & 7) * 8;            // 0..56
        int r = t0 + lr;
        int m = mk[b * T_ + r];
        const float* srcp = &Kf[(long)(b * T_ + r) * 3072 + 1024 + h * 64 + off];
        float4 va = ((const float4*)srcp)[0];
        float4 vb = ((const float4*)srcp)[1];
        float xs[8] = {va.x, va.y, va.z, va.w, vb.x, vb.y, vb.z, vb.w};
        u16x8 wv;
        #pragma unroll
        for (int e = 0; e < 8; e++) {
            float x = (m > 0) ? xs[e] : 0.0f;
            u16 hi = f2b(x);
            wv[e] = (seg == 1) ? f2b(x - b2f(hi)) : hi;
        }
        *(u16x8*)&Ks[((long)sz * T_ + r) * 128 + seg * 64 + off] = wv;
    }
}

// ------- fused flash attention: logical K=192 via 128-phys hi/lo fragment reuse -----
// 512 threads (8 waves x 16 q-rows), KVBLK=64, K/V double-buffered, 64KB LDS.
__global__ __launch_bounds__(512, 4) void flash_comb(const u16* __restrict__ Qs,
                                                     const u16* __restrict__ Ks,
                                                     const u16* __restrict__ Vt,
                                                     u16* __restrict__ ctx2) {
    __shared__ u16 Ksh[2][64 * 128]; // [buf][row][unit c16 ^ (row&7)], 16KB each
    __shared__ u16 Vsh[2][64 * 64];  // [buf][d][unit c16 ^ (d&7)], 8KB each
    __shared__ u16 Psh[128 * 64];    // [q][col ^ ((q&7)<<3)], 16KB (32-bank span)
    const int tid = threadIdx.x, wave = tid >> 6, lane = tid & 63;
    const int z = blockIdx.x;
    const int m0 = blockIdx.y * 128;
    const int h = z & 15;
    const int g = lane >> 4, fr = lane & 15;
    const int wm = wave * 16;
    const u16* Qb = Qs + (long)z * T_ * 128;
    const u16* Kb = Ks + (long)z * T_ * 128;
    const u16* Vb = Vt + (long)z * HD_ * T_;

    // staging: 24 1KB slots (16 K + 8 V); wave w: slots {w, w+8, w+16}
    auto STAGE = [&](int k0, int buf) {
        #pragma unroll
        for (int t = 0; t < 3; t++) {
            int slot = wave + t * 8;
            if (slot < 16) {         // K: 64 rows x 16 units
                int o16 = slot * 64 + lane;
                int row = o16 >> 4, c16 = o16 & 15;
                gl2lds16(Kb + (long)(k0 + row) * 128 + ((c16 ^ (row & 7)) * 8),
                         &Ksh[buf][slot * 512]);
            } else {                 // V: 64 d-rows x 8 units
                int o16 = (slot - 16) * 64 + lane;
                int d = o16 >> 3, c16 = o16 & 7;
                gl2lds16(Vb + (long)d * T_ + k0 + ((c16 ^ (d & 7)) * 8),
                         &Vsh[buf][(slot - 16) * 512]);
            }
        }
    };

    // Q' phys fragments (4): [qhi chunk0, qhi chunk1, qlo chunk0, qlo chunk1]
    bf16x8 qA[4];
    #pragma unroll
    for (int p = 0; p < 4; p++)
        qA[p] = *(const bf16x8*)&Qb[(long)(m0 + wm + fr) * 128 + p * 32 + g * 8];

    f32x4 oacc[4], mrun, lrun;
    mrun = (f32x4){-1e30f, -1e30f, -1e30f, -1e30f};
    lrun = (f32x4){0.f, 0.f, 0.f, 0.f};
    #pragma unroll
    for (int dj = 0; dj < 4; dj++) oacc[dj] = (f32x4){0.f, 0.f, 0.f, 0.f};

    STAGE(0, 0);
    __syncthreads();

    #pragma unroll 1
    for (int kt = 0; kt < 16; kt++) {
        const int buf = kt & 1;
        if (kt < 15) STAGE((kt + 1) * 64, buf ^ 1);   // prefetch overlaps compute

        // S = Q' K^T (16 q-rows x 64 k-cols), logical K=192 via fragment reuse:
        //   S = qhi.khi + qlo.khi + qhi.klo  (chunked over 2 MFMA k-slices each)
        f32x4 sacc[4];
        #pragma unroll
        for (int ki = 0; ki < 4; ki++) sacc[ki] = (f32x4){0.f, 0.f, 0.f, 0.f};
        __builtin_amdgcn_s_setprio(1);
        {
            bf16x8 kb[2][4];
            // khi chunks (units [0,8))
            #pragma unroll
            for (int pk = 0; pk < 2; pk++)
                #pragma unroll
                for (int ki = 0; ki < 4; ki++) {
                    int row = ki * 16 + fr;
                    kb[pk][ki] = *(const bf16x8*)&Ksh[buf][row * 128 + (((pk * 4 + g) ^ (row & 7)) * 8)];
                }
            #pragma unroll
            for (int ki = 0; ki < 4; ki++) {
                sacc[ki] = __builtin_amdgcn_mfma_f32_16x16x32_bf16(qA[0], kb[0][ki], sacc[ki], 0, 0, 0);
                sacc[ki] = __builtin_amdgcn_mfma_f32_16x16x32_bf16(qA[1], kb[1][ki], sacc[ki], 0, 0, 0);
                sacc[ki] = __builtin_amdgcn_mfma_f32_16x16x32_bf16(qA[2], kb[0][ki], sacc[ki], 0, 0, 0);
                sacc[ki] = __builtin_amdgcn_mfma_f32_16x16x32_bf16(qA[3], kb[1][ki], sacc[ki], 0, 0, 0);
            }
            // klo chunks (units [8,16))
            #pragma unroll
            for (int pk = 0; pk < 2; pk++)
                #pragma unroll
                for (int ki = 0; ki < 4; ki++) {
                    int row = ki * 16 + fr;
                    kb[pk][ki] = *(const bf16x8*)&Ksh[buf][row * 128 + ((((pk + 2) * 4 + g) ^ (row & 7)) * 8)];
                }
            #pragma unroll
            for (int ki = 0; ki < 4; ki++) {
                sacc[ki] = __builtin_amdgcn_mfma_f32_16x16x32_bf16(qA[0], kb[0][ki], sacc[ki], 0, 0, 0);
                sacc[ki] = __builtin_amdgcn_mfma_f32_16x16x32_bf16(qA[1], kb[1][ki], sacc[ki], 0, 0, 0);
            }
        }
        __builtin_amdgcn_s_setprio(0);

        // online softmax in C-layout: row = wm + g*4+e, col = ki*16+fr; tree max
        f32x4 tm;
        #pragma unroll
        for (int e = 0; e < 4; e++)
            tm[e] = fmaxf(fmaxf(sacc[0][e], sacc[1][e]), fmaxf(sacc[2][e], sacc[3][e]));
        #pragma unroll
        for (int off = 1; off < 16; off <<= 1)
            #pragma unroll
            for (int e = 0; e < 4; e++) tm[e] = fmaxf(tm[e], shx(tm[e], off));

        // defer-max (T13): only rescale when tile max grew past mrun + 8
        int within = (tm[0] <= mrun[0] + 8.f) && (tm[1] <= mrun[1] + 8.f) &&
                     (tm[2] <= mrun[2] + 8.f) && (tm[3] <= mrun[3] + 8.f);
        if (!__all(within)) {
            f32x4 alpha;
            #pragma unroll
            for (int e = 0; e < 4; e++) {
                float mnew = fmaxf(mrun[e], tm[e]);
                alpha[e] = __expf(mrun[e] - mnew);
                mrun[e] = mnew;
            }
            #pragma unroll
            for (int dj = 0; dj < 4; dj++)
                #pragma unroll
                for (int e = 0; e < 4; e++) oacc[dj][e] *= alpha[e];
            #pragma unroll
            for (int e = 0; e < 4; e++) lrun[e] *= alpha[e];
        }

        f32x4 psum = (f32x4){0.f, 0.f, 0.f, 0.f};
        #pragma unroll
        for (int ki = 0; ki < 4; ki++) {
            #pragma unroll
            for (int e = 0; e < 4; e++) {
                float p = __expf(sacc[ki][e] - mrun[e]);
                psum[e] += p;
                int row = wm + g * 4 + e;
                Psh[row * 64 + ((ki * 16 + fr) ^ ((row & 7) << 3))] = f2b(p);
            }
        }
        #pragma unroll
        for (int off = 1; off < 16; off <<= 1)
            #pragma unroll
            for (int e = 0; e < 4; e++) psum[e] += shx(psum[e], off);
        #pragma unroll
        for (int e = 0; e < 4; e++) lrun[e] += psum[e];

        // PV: O += P @ V (P via LDS round-trip C-layout -> A-layout, wave-private)
        bf16x8 pa[2];
        #pragma unroll
        for (int ks = 0; ks < 2; ks++) {
            int row = wm + fr;
            pa[ks] = *(const bf16x8*)&Psh[row * 64 + (((ks * 4 + g) ^ (row & 7)) * 8)];
        }
        __builtin_amdgcn_s_setprio(1);
        #pragma unroll
        for (int dj = 0; dj < 4; dj++) {
            int d = dj * 16 + fr;
            bf16x8 vb0 = *(const bf16x8*)&Vsh[buf][d * 64 + (((0 * 4 + g) ^ (d & 7)) * 8)];
            bf16x8 vb1 = *(const bf16x8*)&Vsh[buf][d * 64 + (((1 * 4 + g) ^ (d & 7)) * 8)];
            oacc[dj] = __builtin_amdgcn_mfma_f32_16x16x32_bf16(pa[0], vb0, oacc[dj], 0, 0, 0);
            oacc[dj] = __builtin_amdgcn_mfma_f32_16x16x32_bf16(pa[1], vb1, oacc[dj], 0, 0, 0);
        }
        __builtin_amdgcn_s_setprio(0);
        __syncthreads();   // drains prefetch vmcnt (overlapped) + guards buf reuse
    }

    // epilogue: O /= l; ctx2 flat [4096][1024], row = (z>>4)*T + qr
    f32x4 inv;
    #pragma unroll
    for (int e = 0; e < 4; e++) inv[e] = 1.f / lrun[e];
    #pragma unroll
    for (int dj = 0; dj < 4; dj++)
        #pragma unroll
        for (int e = 0; e < 4; e++) {
            int qr = m0 + wm + g * 4 + e;
            int dc = dj * 16 + fr;
            ctx2[((long)((z >> 4) * T_ + qr)) * D_ + h * 64 + dc] = f2b(oacc[dj][e] * inv[e]);
        }
}

// ------- fused residual-add + LayerNorm, dual-stream batched (4096 rows) ------------
template <bool XF32, bool OUTF32>
__global__ __launch_bounds__(256) void ln_fused2(const void* __restrict__ x0,
                                                 const void* __restrict__ x1,
                                                 const u16* __restrict__ y,
                                                 const float* __restrict__ g,
                                                 const float* __restrict__ be,
                                                 void* __restrict__ out) {
    __shared__ float red[8];
    int row = blockIdx.x;
    const void* xp = (row < 2048) ? x0 : x1;
    long xbase = (long)((row < 2048) ? row : row - 2048) * 1024;
    long base = (long)row * 1024;
    int tid = threadIdx.x, wave = tid >> 6, lane = tid & 63;
    float v[4];
    #pragma unroll
    for (int i = 0; i < 4; i++) {
        int c = tid + i * 256;
        float xv = XF32 ? ((const float*)xp)[xbase + c] : b2f(((const u16*)xp)[xbase + c]);
        v[i] = xv + b2f(y[base + c]);
    }
    float s = v[0] + v[1] + v[2] + v[3];
    float q = v[0] * v[0] + v[1] * v[1] + v[2] * v[2] + v[3] * v[3];
    s = wred_sum(s);
    q = wred_sum(q);
    if (lane == 0) { red[wave] = s; red[4 + wave] = q; }
    __syncthreads();
    s = red[0] + red[1] + red[2] + red[3];
    q = red[4] + red[5] + red[6] + red[7];
    float mean = s * (1.f / 1024.f);
    float var = q * (1.f / 1024.f) - mean * mean;
    float inv = rsqrtf(var + 1e-5f);
    #pragma unroll
    for (int i = 0; i < 4; i++) {
        int c = tid + i * 256;
        float o = (v[i] - mean) * inv * g[c] + be[c];
        if (OUTF32) ((float*)out)[base + c] = o;
        else ((u16*)out)[base + c] = f2b(o);
    }
}

extern "C" void kernel_launch(void* const* d_in, const int* in_sizes, int n_in,
                              void* d_out, int out_size, void* d_ws, size_t ws_size,
                              hipStream_t stream) {
    const float* src = (const float*)d_in[0];
    const float* aux = (const float*)d_in[1];
    const float* Wu = (const float*)d_in[2];
    const float* bu = (const float*)d_in[3];
    const float* Wv = (const float*)d_in[4];
    const float* bv = (const float*)d_in[5];
    const float* Wo = (const float*)d_in[6];
    const float* bo = (const float*)d_in[7];
    const float* W1 = (const float*)d_in[8];
    const float* b1 = (const float*)d_in[9];
    const float* W2 = (const float*)d_in[10];
    const float* b2 = (const float*)d_in[11];
    const float* g1 = (const float*)d_in[12];
    const float* be1 = (const float*)d_in[13];
    const float* g2 = (const float*)d_in[14];
    const float* be2 = (const float*)d_in[15];
    const int* src_mask = (const int*)d_in[16];
    const int* aux_mask = (const int*)d_in[17];

    // -------- workspace (time-phased; ~148 MiB peak < 159 proven) --------------------
    char* w = (char*)d_ws;
    auto alloc = [&](size_t bytes) { char* p = w; w += (bytes + 255) & ~(size_t)255; return p; };
    // permanent (~59 MiB)
    u16* WoT = (u16*)alloc(1024L * 1024 * 2);
    u16* W1T = (u16*)alloc(4096L * 1024 * 2);
    u16* W2T = (u16*)alloc(1024L * 4096 * 2);
    u16* Vt  = (u16*)alloc(64L * 64 * 1024 * 2);
    float* RS = (float*)alloc(64L * 4096 * 4);
    u16* Qs = (u16*)alloc(64L * 1024 * 128 * 2);    // [qhi|qlo] 128-phys
    u16* Ks = (u16*)alloc(64L * 1024 * 128 * 2);    // [khi|klo] 128-phys
    // scratch union: 89 MiB, two time-phases
    char* scratch = (char*)alloc(89L * 1024 * 1024);
    // phase A: WS2 (both split weights), As2 (both split inputs), UVf (both outputs)
    u16* WS2 = (u16*)(scratch);                        // 25165824 (2 x 3072x2048 bf16)
    u16* As2 = (u16*)(scratch + 25165824L);            // 16777216 (2 x 2048x2048 bf16)
    float* UVf = (float*)(scratch + 41943040L);        // 50331648 (2 x 2048x3072 f32)
    float* Uf = UVf;
    float* Vf = UVf + 6291456L;
    float* RSp = (float*)(scratch);                    // 16777216 (aliases dead WS2)
    // phase B (overlays phase-A scratch, all of which is dead by then)
    u16* ctx2   = (u16*)(scratch);                     // 8388608  [4096][1024] bf16
    u16* attn_s = (u16*)(scratch + 8388608L);          // 8388608
    u16* o1s    = (u16*)(scratch + 16777216L);         // 8388608
    u16* hbuf   = (u16*)(scratch + 25165824L);         // 33554432 [2][2048][4096]
    u16* fbuf   = (u16*)(scratch + 58720256L);         // 8388608  (ends 67108864)

    // -------- phase A: weight prep + hi/lo QKV projections + R/S + Q'/K splits ------
    transpose_cvt<<<dim3(16, 16), 256, 0, stream>>>(Wo, WoT, 1024, 1024);
    transpose_cvt<<<dim3(64, 16), 256, 0, stream>>>(W1, W1T, 1024, 4096);
    transpose_cvt<<<dim3(16, 64), 256, 0, stream>>>(W2, W2T, 4096, 1024);

    wsplit2<<<dim3(48, 16), 256, 0, stream>>>(Wu, WS2, 1024, 3072);
    wsplit2<<<dim3(48, 16), 256, 0, stream>>>(Wv, WS2 + 6291456L, 1024, 3072);
    split2<<<dim3(2048, 2), 256, 0, stream>>>(src, aux, As2);
    gemm_hl<<<dim3(16, 24, 2), 256, 0, stream>>>(
        As2, WS2, UVf, bu, bv, 4194304L, 6291456L, 6291456L);
    // WS2/As2 dead from here; RSp aliases
    repack_vt<<<dim3(16, 64), 256, 0, stream>>>(Uf, Vf, Vt);
    rs_part<<<dim3(64, 16), 256, 0, stream>>>(Uf, Vf, src_mask, aux_mask, RSp);
    rs_reduce<<<256, 256, 0, stream>>>(RSp, RS);
    qprime<<<dim3(8, 64), 256, 0, stream>>>(Uf, Vf, RS, Qs);
    ksplit<<<dim3(16, 64), 256, 0, stream>>>(Uf, Vf, src_mask, aux_mask, Ks);
    // ---- phase A scratch dead; phase B overlays -------------------------------------

    // fused comb + softmax + PV for all 64 (s,b,h) slices in one launch
    flash_comb<<<dim3(64, 8), 512, 0, stream>>>(Qs, Ks, Vt, ctx2);

    // -------- phase B: dual-stream batched (z = stream), BK=64 GEMMs -----------------
    gemm64<EPI_BF16_BIAS, 64><<<dim3(16, 16, 2), 256, 0, stream>>>(
        ctx2, WoT, attn_s, bo, 2048, 1024, 1024, 1024, 1024, 1024,
        2048L * 1024, 0, 2048L * 1024);
    ln_fused2<true, false><<<4096, 256, 0, stream>>>(src, aux, attn_s, g1, be1, o1s);
    gemm64<EPI_BF16_BIAS_RELU, 128><<<dim3(16, 32, 2), 256, 0, stream>>>(
        o1s, W1T, hbuf, b1, 2048, 4096, 1024, 1024, 1024, 4096,
        2048L * 1024, 0, 2048L * 4096);
    gemm64<EPI_BF16_BIAS, 64><<<dim3(16, 16, 2), 256, 0, stream>>>(
        hbuf, W2T, fbuf, b2, 2048, 1024, 4096, 4096, 4096, 1024,
        2048L * 4096, 0, 2048L * 1024);
    ln_fused2<false, true><<<4096, 256, 0, stream>>>(o1s, o1s + 2048L * 1024, fbuf,
                                                     g2, be2, (float*)d_out);
}